// Round 8
// baseline (445.851 us; speedup 1.0000x reference)
//
#include <hip/hip_runtime.h>
#include <hip/hip_bf16.h>
#include <math.h>

#define D_STATE   64
#define HEADDIM   64
#define D_INNER   2048
#define NHEADS    32
#define GN        64
#define CONV_DIM  2304
#define D_IN_PROJ 4416
#define ZLD       4352      /* z + xBC columns only (dt handled separately) */
#define K_SP      7
#define K_TP      4
#define CHUNK     256
#define BATCHN    2
#define FRAMES    8
#define SPATIAL   256
#define SEQLEN    2048
#define NCH       8
#define MTOT      4096

typedef __attribute__((ext_vector_type(8))) short short8;
typedef __attribute__((ext_vector_type(8))) unsigned short ushort8v;
typedef __attribute__((ext_vector_type(4))) float floatx4;

__device__ __forceinline__ float silu_f(float x) { return x / (1.f + __expf(-x)); }
__device__ __forceinline__ int flip_l(int l) { return (l & ~7) | (7 - (l & 7)); }
__device__ __forceinline__ unsigned short f2bf(float f) {
  unsigned int u = __float_as_uint(f);
  unsigned int r = (u + 0x7fffu + ((u >> 16) & 1u)) >> 16;
  return (unsigned short)r;
}
__device__ __forceinline__ float bf2f(unsigned short s) {
  return __uint_as_float(((unsigned int)s) << 16);
}
__device__ __forceinline__ void gload_lds16(const unsigned short* g, unsigned short* l) {
  __builtin_amdgcn_global_load_lds((const __attribute__((address_space(1))) void*)g,
                                   (__attribute__((address_space(3))) void*)l, 16, 0, 0);
}

// ---------------- f32 -> bf16 cast (two tensors, one launch) ----------------
__global__ __launch_bounds__(256) void cast2_bf16_kernel(const float* __restrict__ a,
                                                         unsigned short* __restrict__ oa,
                                                         int na_blocks,
                                                         const float* __restrict__ b,
                                                         unsigned short* __restrict__ ob) {
  int bid = blockIdx.x;
  const float* in;
  unsigned short* out;
  size_t i;
  if (bid < na_blocks) {
    in = a; out = oa;
    i = ((size_t)bid * 256 + threadIdx.x) * 4;
  } else {
    in = b; out = ob;
    i = ((size_t)(bid - na_blocks) * 256 + threadIdx.x) * 4;
  }
  float4 v = *(const float4*)(in + i);
  ushort4 o;
  o.x = f2bf(v.x); o.y = f2bf(v.y); o.z = f2bf(v.z); o.w = f2bf(v.w);
  *(ushort4*)(out + i) = o;
}

__global__ __launch_bounds__(256) void cast_bf16_kernel(const float* __restrict__ in,
                                                        unsigned short* __restrict__ out) {
  size_t i = ((size_t)blockIdx.x * 256 + threadIdx.x) * 4;
  float4 v = *(const float4*)(in + i);
  ushort4 o;
  o.x = f2bf(v.x); o.y = f2bf(v.y); o.z = f2bf(v.z); o.w = f2bf(v.w);
  *(ushort4*)(out + i) = o;
}

// XCD-aware block remap: 1D grid nbx*nby (nby % 8 == 0). bid&7 ~ XCD (round-robin
// dispatch); each XCD owns a contiguous stripe of nby/8 m-rows, n iterates fastest
// so an A-tile is fetched into exactly one per-XCD L2.
__device__ __forceinline__ void swizzle_mn(int nbx, int nby, int& m0, int& n0) {
  int bid = blockIdx.x;
  int x = bid & 7;
  int j = bid >> 3;
  int mper = nby >> 3;
  m0 = (x * mper + j / nbx) * 128;
  n0 = (j % nbx) * 128;
}

// ---------------- bf16 MFMA GEMM (f32 out): C = A * B^T ----------------
__global__ __launch_bounds__(256) void gemm_bf16(
    const unsigned short* __restrict__ A, int lda,
    const unsigned short* __restrict__ B, int ldb,
    float* __restrict__ C, int ldc, int K, int nbx, int nby) {
  __shared__ unsigned short As[128 * 32];
  __shared__ unsigned short Bs[128 * 32];
  const int tid = threadIdx.x;
  const int lane = tid & 63;
  const int w = tid >> 6;
  int m0, n0;
  swizzle_mn(nbx, nby, m0, n0);
  const int wm = (w >> 1) * 64;
  const int wn = (w & 1) * 64;
  const int srow = lane >> 2;
  const int scol = (lane & 3) * 8;
  floatx4 acc[4][4] = {};
  for (int k0 = 0; k0 < K; k0 += 32) {
#pragma unroll
    for (int it = 0; it < 2; ++it) {
      int ch = it * 4 + w;
      gload_lds16(A + (size_t)(m0 + ch * 16 + srow) * lda + k0 + scol, &As[ch * 512]);
      gload_lds16(B + (size_t)(n0 + ch * 16 + srow) * ldb + k0 + scol, &Bs[ch * 512]);
    }
    __syncthreads();
    const int fr = lane & 15;
    const int kq = (lane >> 4) * 8;
    short8 af[4], bfr[4];
#pragma unroll
    for (int i = 0; i < 4; ++i)
      af[i] = *(const short8*)&As[(wm + i * 16 + fr) * 32 + kq];
#pragma unroll
    for (int j = 0; j < 4; ++j)
      bfr[j] = *(const short8*)&Bs[(wn + j * 16 + fr) * 32 + kq];
#pragma unroll
    for (int i = 0; i < 4; ++i)
#pragma unroll
      for (int j = 0; j < 4; ++j)
        acc[i][j] = __builtin_amdgcn_mfma_f32_16x16x32_bf16(af[i], bfr[j], acc[i][j], 0, 0, 0);
    __syncthreads();
  }
  const int col = lane & 15;
  const int rg = (lane >> 4) * 4;
#pragma unroll
  for (int i = 0; i < 4; ++i)
#pragma unroll
    for (int j = 0; j < 4; ++j)
#pragma unroll
      for (int r = 0; r < 4; ++r)
        C[(size_t)(m0 + wm + i * 16 + rg + r) * ldc + (n0 + wn + j * 16 + col)] = acc[i][j][r];
}

// ---------------- bf16 MFMA GEMM (bf16 out, vectorized epilogue) ----------------
__global__ __launch_bounds__(256) void gemm_bf16_bf16out(
    const unsigned short* __restrict__ A, int lda,
    const unsigned short* __restrict__ B, int ldb,
    unsigned short* __restrict__ C, int ldc, int K, int nbx, int nby) {
  __shared__ unsigned short As[128 * 32];
  __shared__ unsigned short Bs[128 * 32];
  const int tid = threadIdx.x;
  const int lane = tid & 63;
  const int w = tid >> 6;
  int m0, n0;
  swizzle_mn(nbx, nby, m0, n0);
  const int wm = (w >> 1) * 64;
  const int wn = (w & 1) * 64;
  const int srow = lane >> 2;
  const int scol = (lane & 3) * 8;
  floatx4 acc[4][4] = {};
  for (int k0 = 0; k0 < K; k0 += 32) {
#pragma unroll
    for (int it = 0; it < 2; ++it) {
      int ch = it * 4 + w;
      gload_lds16(A + (size_t)(m0 + ch * 16 + srow) * lda + k0 + scol, &As[ch * 512]);
      gload_lds16(B + (size_t)(n0 + ch * 16 + srow) * ldb + k0 + scol, &Bs[ch * 512]);
    }
    __syncthreads();
    const int fr = lane & 15;
    const int kq = (lane >> 4) * 8;
    short8 af[4], bfr[4];
#pragma unroll
    for (int i = 0; i < 4; ++i)
      af[i] = *(const short8*)&As[(wm + i * 16 + fr) * 32 + kq];
#pragma unroll
    for (int j = 0; j < 4; ++j)
      bfr[j] = *(const short8*)&Bs[(wn + j * 16 + fr) * 32 + kq];
#pragma unroll
    for (int i = 0; i < 4; ++i)
#pragma unroll
      for (int j = 0; j < 4; ++j)
        acc[i][j] = __builtin_amdgcn_mfma_f32_16x16x32_bf16(af[i], bfr[j], acc[i][j], 0, 0, 0);
    __syncthreads();
  }
  // epilogue: per-wave LDS transpose (reuse As), ushort8 coalesced stores
  const int fr = lane & 15;
  const int rg = (lane >> 4) * 4;
  unsigned short* Ew = &As[w * 1024];
  const int rr = lane >> 3;
  const int c8 = (lane & 7) * 8;
#pragma unroll
  for (int i = 0; i < 4; ++i) {
#pragma unroll
    for (int q = 0; q < 4; ++q)
#pragma unroll
      for (int j = 0; j < 4; ++j)
        Ew[(rg + q) * 64 + j * 16 + fr] = f2bf(acc[i][j][q]);
    ushort8v v0 = *(const ushort8v*)&Ew[rr * 64 + c8];
    ushort8v v1 = *(const ushort8v*)&Ew[(rr + 8) * 64 + c8];
    *(ushort8v*)(C + (size_t)(m0 + wm + i * 16 + rr) * ldc + n0 + wn + c8) = v0;
    *(ushort8v*)(C + (size_t)(m0 + wm + i * 16 + rr + 8) * ldc + n0 + wn + c8) = v1;
  }
}

// ---------------- skinny f32 GEMM: C[M x N(<=64)] = A * B^T, M-tile=16 ----------------
__global__ __launch_bounds__(256) void gemm_skinny_f32(
    const float* __restrict__ A, int lda,
    const float* __restrict__ B, int ldb,
    float* __restrict__ C, int ldc, int N, int K) {
  __shared__ float Bs[64][68];
  __shared__ float As[16][68];
  const int tid = threadIdx.x;
  const int m0 = blockIdx.x * 16;
  const int tm = tid >> 4;
  const int tn4 = (tid & 15) * 4;
  float acc[4] = {0.f, 0.f, 0.f, 0.f};
  for (int k0 = 0; k0 < K; k0 += 64) {
    __syncthreads();
    {
      int bn = tid >> 2;
      int bk = (tid & 3) * 16;
      if (bn < N) {
#pragma unroll
        for (int q = 0; q < 4; ++q) {
          float4 v = *(const float4*)(B + (size_t)bn * ldb + k0 + bk + q * 4);
          Bs[bk + q*4 + 0][bn] = v.x;
          Bs[bk + q*4 + 1][bn] = v.y;
          Bs[bk + q*4 + 2][bn] = v.z;
          Bs[bk + q*4 + 3][bn] = v.w;
        }
      } else {
#pragma unroll
        for (int q = 0; q < 4; ++q) {
          Bs[bk + q*4 + 0][bn] = 0.f;
          Bs[bk + q*4 + 1][bn] = 0.f;
          Bs[bk + q*4 + 2][bn] = 0.f;
          Bs[bk + q*4 + 3][bn] = 0.f;
        }
      }
      int am = tid >> 4;
      int ak = (tid & 15) * 4;
      *(float4*)&As[am][ak] = *(const float4*)(A + (size_t)(m0 + am) * lda + k0 + ak);
    }
    __syncthreads();
#pragma unroll 8
    for (int k = 0; k < 64; ++k) {
      float a = As[tm][k];
      float4 b4 = *(const float4*)&Bs[k][tn4];
      acc[0] += a * b4.x; acc[1] += a * b4.y;
      acc[2] += a * b4.z; acc[3] += a * b4.w;
    }
  }
  if (tn4 < N)
    *(float4*)(C + (size_t)(m0 + tm) * ldc + tn4) = make_float4(acc[0], acc[1], acc[2], acc[3]);
}

// ---------------- skinny GEMM, bf16 A: C[M x N(<=64)] = A * B^T ----------------
__global__ __launch_bounds__(256) void gemm_skinny_a16(
    const unsigned short* __restrict__ A, int lda,
    const float* __restrict__ B, int ldb,
    float* __restrict__ C, int ldc, int N, int K) {
  __shared__ float Bs[64][68];
  __shared__ float As[16][68];
  const int tid = threadIdx.x;
  const int m0 = blockIdx.x * 16;
  const int tm = tid >> 4;
  const int tn4 = (tid & 15) * 4;
  float acc[4] = {0.f, 0.f, 0.f, 0.f};
  for (int k0 = 0; k0 < K; k0 += 64) {
    __syncthreads();
    {
      int bn = tid >> 2;
      int bk = (tid & 3) * 16;
      if (bn < N) {
#pragma unroll
        for (int q = 0; q < 4; ++q) {
          float4 v = *(const float4*)(B + (size_t)bn * ldb + k0 + bk + q * 4);
          Bs[bk + q*4 + 0][bn] = v.x;
          Bs[bk + q*4 + 1][bn] = v.y;
          Bs[bk + q*4 + 2][bn] = v.z;
          Bs[bk + q*4 + 3][bn] = v.w;
        }
      } else {
#pragma unroll
        for (int q = 0; q < 4; ++q) {
          Bs[bk + q*4 + 0][bn] = 0.f;
          Bs[bk + q*4 + 1][bn] = 0.f;
          Bs[bk + q*4 + 2][bn] = 0.f;
          Bs[bk + q*4 + 3][bn] = 0.f;
        }
      }
      int am = tid >> 4;
      int ak = (tid & 15) * 4;
      ushort4 v = *(const ushort4*)(A + (size_t)(m0 + am) * lda + k0 + ak);
      As[am][ak+0] = bf2f(v.x); As[am][ak+1] = bf2f(v.y);
      As[am][ak+2] = bf2f(v.z); As[am][ak+3] = bf2f(v.w);
    }
    __syncthreads();
#pragma unroll 8
    for (int k = 0; k < 64; ++k) {
      float a = As[tm][k];
      float4 b4 = *(const float4*)&Bs[k][tn4];
      acc[0] += a * b4.x; acc[1] += a * b4.y;
      acc[2] += a * b4.z; acc[3] += a * b4.w;
    }
  }
  if (tn4 < N)
    *(float4*)(C + (size_t)(m0 + tm) * ldc + tn4) = make_float4(acc[0], acc[1], acc[2], acc[3]);
}

// ---------------- dt = softplus(dt_raw + bias), flip for reverse; + chunk-local cumsum ----------------
__global__ __launch_bounds__(256) void dtscan_kernel(const float* __restrict__ DTraw,
                                                     const float* __restrict__ dt_bias,
                                                     const float* __restrict__ A_log,
                                                     float* __restrict__ DTt,
                                                     float* __restrict__ CUMS) {
  __shared__ float sc[256];
  int tid = threadIdx.x;
  int idx = blockIdx.x * 256 + tid;
  int l  = idx & 2047;
  int rh = idx >> 11;
  int h  = rh & 31;
  int r  = rh >> 5;
  int bi = r & 1;
  int ls = (r < 2) ? l : flip_l(l);
  int ch = (r < 2) ? h : NHEADS + h;
  float raw = DTraw[((size_t)bi * SEQLEN + ls) * 64 + ch] + dt_bias[h];
  float dtv = (raw > 20.f) ? raw : log1pf(__expf(raw));
  DTt[idx] = dtv;
  float A = -__expf(A_log[h]);
  float run = dtv * A;
  sc[tid] = run;
  __syncthreads();
#pragma unroll
  for (int ofs = 1; ofs < 256; ofs <<= 1) {
    float add = (tid >= ofs) ? sc[tid - ofs] : 0.f;
    __syncthreads();
    run += add;
    sc[tid] = run;
    __syncthreads();
  }
  CUMS[idx] = run;
}

// ---------------- fused convs: bf16 in/out, register sliding-window ----------------
__global__ __launch_bounds__(256) void conv_fused2_kernel(const unsigned short* __restrict__ Zb,
                                                          const float* __restrict__ wsp,
                                                          const float* __restrict__ bsp,
                                                          const float* __restrict__ wtp,
                                                          const float* __restrict__ btp,
                                                          unsigned short* __restrict__ XTb) {
  __shared__ float4 xsl[8][8][32];
  const int tid = threadIdx.x;
  const int g  = tid & 31;
  const int fr = tid >> 5;
  const int c  = blockIdx.x * 128 + g * 4;
  const int s0 = blockIdx.y * 8;
  const int bi = blockIdx.z;
  float wsp_r[4][K_SP];
#pragma unroll
  for (int ch = 0; ch < 4; ++ch)
#pragma unroll
    for (int j = 0; j < K_SP; ++j) wsp_r[ch][j] = wsp[(c + ch) * K_SP + j];
  float4 bsp4 = *(const float4*)(bsp + c);
  float4 z[14];
#pragma unroll
  for (int i = 0; i < 14; ++i) {
    int ss = s0 - 3 + i;
    if (0 <= ss && ss < SPATIAL) {
      ushort4 v = *(const ushort4*)(Zb + ((size_t)bi * SEQLEN + (ss*8 + fr)) * ZLD + D_INNER + c);
      z[i] = make_float4(bf2f(v.x), bf2f(v.y), bf2f(v.z), bf2f(v.w));
    } else {
      z[i] = make_float4(0.f, 0.f, 0.f, 0.f);
    }
  }
#pragma unroll
  for (int so = 0; so < 8; ++so) {
    float4 a = bsp4;
#pragma unroll
    for (int j = 0; j < K_SP; ++j) {
      a.x += wsp_r[0][j] * z[so + j].x;
      a.y += wsp_r[1][j] * z[so + j].y;
      a.z += wsp_r[2][j] * z[so + j].z;
      a.w += wsp_r[3][j] * z[so + j].w;
    }
    a.x = silu_f(a.x); a.y = silu_f(a.y); a.z = silu_f(a.z); a.w = silu_f(a.w);
    xsl[fr][so][g] = a;
  }
  __syncthreads();
  float wtp_r[4][K_TP];
#pragma unroll
  for (int ch = 0; ch < 4; ++ch)
#pragma unroll
    for (int j = 0; j < K_TP; ++j) wtp_r[ch][j] = wtp[(c + ch) * K_TP + j];
  float4 btp4 = *(const float4*)(btp + c);
#pragma unroll
  for (int so = 0; so < 8; ++so) {
    float4 t = btp4;
#pragma unroll
    for (int j = 0; j < K_TP; ++j) {
      int ff = fr + j - (K_TP - 1);
      if (ff >= 0) {
        float4 xv = xsl[ff][so][g];
        t.x += wtp_r[0][j] * xv.x;
        t.y += wtp_r[1][j] * xv.y;
        t.z += wtp_r[2][j] * xv.z;
        t.w += wtp_r[3][j] * xv.w;
      }
    }
    ushort4 o;
    o.x = f2bf(silu_f(t.x)); o.y = f2bf(silu_f(t.y));
    o.z = f2bf(silu_f(t.z)); o.w = f2bf(silu_f(t.w));
    *(ushort4*)(XTb + ((size_t)bi * SEQLEN + ((s0 + so)*8 + fr)) * CONV_DIM + c) = o;
  }
}

// ---------------- CB[t][s] = sum_n C[t][n] B[s][n], per (r,c)  (t-major) ----------------
__global__ __launch_bounds__(256) void cb_kernel(const unsigned short* __restrict__ XTb,
                                                 float* __restrict__ CBs) {
  __shared__ float Ct[64][65];
  __shared__ float Bt[64][65];
  int tid = threadIdx.x;
  int t0 = (blockIdx.x & 3) * 64;
  int s0 = (blockIdx.x >> 2) * 64;
  if (s0 > t0) return;
  int c = blockIdx.y;
  int r = blockIdx.z;
  int bi = r & 1;
  int bOff = D_INNER + ((r < 2) ? 0 : 2*GN);
  int cOff = bOff + GN;
  int lrow = tid >> 4;
  int n4 = (tid & 15) << 2;
#pragma unroll
  for (int rep = 0; rep < 4; ++rep) {
    int tl = rep * 16 + lrow;
    int Lc = c * CHUNK + t0 + tl;
    int Ls = c * CHUNK + s0 + tl;
    if (r >= 2) { Lc = flip_l(Lc); Ls = flip_l(Ls); }
    ushort4 cv = *(const ushort4*)(XTb + ((size_t)bi*SEQLEN + Lc)*CONV_DIM + cOff + n4);
    ushort4 bv = *(const ushort4*)(XTb + ((size_t)bi*SEQLEN + Ls)*CONV_DIM + bOff + n4);
    Ct[n4+0][tl] = bf2f(cv.x); Ct[n4+1][tl] = bf2f(cv.y);
    Ct[n4+2][tl] = bf2f(cv.z); Ct[n4+3][tl] = bf2f(cv.w);
    Bt[n4+0][tl] = bf2f(bv.x); Bt[n4+1][tl] = bf2f(bv.y);
    Bt[n4+2][tl] = bf2f(bv.z); Bt[n4+3][tl] = bf2f(bv.w);
  }
  __syncthreads();
  int txx = tid & 15;
  int tyy = tid >> 4;
  float acc[4][4] = {{0.f,0.f,0.f,0.f},{0.f,0.f,0.f,0.f},{0.f,0.f,0.f,0.f},{0.f,0.f,0.f,0.f}};
#pragma unroll
  for (int n = 0; n < D_STATE; ++n) {
    float cr[4], br[4];
#pragma unroll
    for (int i = 0; i < 4; ++i) cr[i] = Ct[n][tyy + 16*i];
#pragma unroll
    for (int j = 0; j < 4; ++j) br[j] = Bt[n][txx + 16*j];
#pragma unroll
    for (int i = 0; i < 4; ++i)
#pragma unroll
      for (int j = 0; j < 4; ++j)
        acc[i][j] += cr[i] * br[j];
  }
  size_t base = (((size_t)r*NCH + c) * CHUNK) * CHUNK;
#pragma unroll
  for (int i = 0; i < 4; ++i)
#pragma unroll
    for (int j = 0; j < 4; ++j)
      CBs[base + (size_t)(t0 + tyy + 16*i)*CHUNK + (s0 + txx + 16*j)] = acc[i][j];
}

// ---------------- per-chunk state sums (MFMA, forward r=0,1 only) ----------------
__global__ __launch_bounds__(256) void chunk_state_kernel(const unsigned short* __restrict__ XTb,
                                                          const float* __restrict__ DTt,
                                                          const float* __restrict__ CUMS,
                                                          float* __restrict__ SCH) {
  __shared__ unsigned short Xb[64][40];
  __shared__ unsigned short Bb[64][40];
  int tid = threadIdx.x;
  int lane = tid & 63;
  int w = tid >> 6;
  int c = blockIdx.x;
  int h = blockIdx.y;
  int r = blockIdx.z;
  int bi = r;
  int rh = r * NHEADS + h;
  float cl = CUMS[(size_t)rh*SEQLEN + c*CHUNK + 255];
  const int fr = lane & 15;
  const int kq = (lane >> 4) * 8;
  floatx4 acc[4] = {};
  for (int sl = 0; sl < 8; ++sl) {
    int s0 = sl * 32;
    __syncthreads();
    {
      int srow = tid >> 3;
      int cg = (tid & 7) * 8;
      int l = c*CHUNK + s0 + srow;
      float g = __expf(cl - CUMS[(size_t)rh*SEQLEN + l]) * DTt[(size_t)rh*SEQLEN + l];
      const unsigned short* row = XTb + ((size_t)bi*SEQLEN + l)*CONV_DIM;
      ushort4 x0 = *(const ushort4*)(row + h*HEADDIM + cg);
      ushort4 x1 = *(const ushort4*)(row + h*HEADDIM + cg + 4);
      ushort4 b0 = *(const ushort4*)(row + D_INNER + cg);
      ushort4 b1 = *(const ushort4*)(row + D_INNER + cg + 4);
      Xb[cg+0][srow] = f2bf(g*bf2f(x0.x)); Xb[cg+1][srow] = f2bf(g*bf2f(x0.y));
      Xb[cg+2][srow] = f2bf(g*bf2f(x0.z)); Xb[cg+3][srow] = f2bf(g*bf2f(x0.w));
      Xb[cg+4][srow] = f2bf(g*bf2f(x1.x)); Xb[cg+5][srow] = f2bf(g*bf2f(x1.y));
      Xb[cg+6][srow] = f2bf(g*bf2f(x1.z)); Xb[cg+7][srow] = f2bf(g*bf2f(x1.w));
      Bb[cg+0][srow] = b0.x; Bb[cg+1][srow] = b0.y;
      Bb[cg+2][srow] = b0.z; Bb[cg+3][srow] = b0.w;
      Bb[cg+4][srow] = b1.x; Bb[cg+5][srow] = b1.y;
      Bb[cg+6][srow] = b1.z; Bb[cg+7][srow] = b1.w;
    }
    __syncthreads();
    short8 af = *(const short8*)&Xb[w*16 + fr][kq];
#pragma unroll
    for (int j = 0; j < 4; ++j) {
      short8 bf8 = *(const short8*)&Bb[j*16 + fr][kq];
      acc[j] = __builtin_amdgcn_mfma_f32_16x16x32_bf16(af, bf8, acc[j], 0, 0, 0);
    }
  }
  const int col = lane & 15;
  const int rg = (lane >> 4) * 4;
  size_t base = (((size_t)r*NCH + c)*NHEADS + h) * (size_t)(HEADDIM*D_STATE);
#pragma unroll
  for (int j = 0; j < 4; ++j)
#pragma unroll
    for (int q = 0; q < 4; ++q)
      SCH[base + (size_t)(w*16 + rg + q)*D_STATE + j*16 + col] = acc[j][q];
}

// ---------------- prefix-combine chunk states -> SPREV ----------------
__global__ __launch_bounds__(256) void state_combine_kernel(const float* __restrict__ SCH,
                                                            const float* __restrict__ CUMS,
                                                            float* __restrict__ SPREV) {
  int bid = blockIdx.x;
  int pq = bid & 3;
  int h = (bid >> 2) & 31;
  int r = bid >> 7;
  int tid = threadIdx.x;
  int p = pq*16 + (tid >> 4);
  int n = (tid & 15) * 4;
  float4 S = make_float4(0.f, 0.f, 0.f, 0.f);
  for (int c = 0; c < NCH; ++c) {
    size_t off = ((((size_t)r*NCH + c)*NHEADS + h)*HEADDIM + p)*D_STATE + n;
    *(float4*)(SPREV + off) = S;
    float dec = __expf(CUMS[((size_t)r*NHEADS + h)*SEQLEN + c*CHUNK + 255]);
    float4 v = *(const float4*)(SCH + off);
    S.x = dec*S.x + v.x; S.y = dec*S.y + v.y;
    S.z = dec*S.z + v.z; S.w = dec*S.w + v.w;
  }
}

// ---------------- Y = intra(triangular, MFMA) + inter (MFMA, fwd only) ----------------
__global__ __launch_bounds__(256) void yscan_kernel(const unsigned short* __restrict__ XTb,
                                                    const float* __restrict__ DTt,
                                                    const float* __restrict__ CUMS,
                                                    const float* __restrict__ CBs,
                                                    const float* __restrict__ SPREV,
                                                    float* __restrict__ Y) {
  __shared__ unsigned short Xb[64][40];
  __shared__ float dts[CHUNK];
  __shared__ float cums[CHUNK];
  int tid = threadIdx.x;
  int lane = tid & 63;
  int w = tid >> 6;
  int c = blockIdx.x;
  int rh = blockIdx.y;
  int h = rh & 31;
  int r = rh >> 5;
  int bi = r & 1;
  dts[tid]  = DTt[(size_t)rh*SEQLEN + c*CHUNK + tid];
  cums[tid] = CUMS[(size_t)rh*SEQLEN + c*CHUNK + tid];
  __syncthreads();
  const int fr = lane & 15;
  const int kq = (lane >> 4) * 8;
  const int wt0 = w * 64;
  float ct[4];
#pragma unroll
  for (int i = 0; i < 4; ++i) ct[i] = cums[wt0 + i*16 + fr];
  floatx4 acc[4][4] = {};
  size_t cbbase = (((size_t)r*NCH + c) * CHUNK) * CHUNK;
  const int maxsl = 2*w + 1;
  for (int sl = 0; sl < 8; ++sl) {
    int s0 = sl * 32;
    __syncthreads();
    {
      int srow = tid >> 3;
      int p0 = (tid & 7) * 4;
      int L = c*CHUNK + s0 + srow;
      if (r >= 2) L = flip_l(L);
      const unsigned short* xrow = XTb + ((size_t)bi*SEQLEN + L)*CONV_DIM + h*HEADDIM;
#pragma unroll
      for (int half = 0; half < 2; ++half) {
        ushort4 v = *(const ushort4*)(xrow + p0 + half*32);
        Xb[p0 + half*32 + 0][srow] = v.x;
        Xb[p0 + half*32 + 1][srow] = v.y;
        Xb[p0 + half*32 + 2][srow] = v.z;
        Xb[p0 + half*32 + 3][srow] = v.w;
      }
    }
    __syncthreads();
    if (sl <= maxsl) {
      float cs[8], dtv[8];
#pragma unroll
      for (int j = 0; j < 8; ++j) { cs[j] = cums[s0 + kq + j]; dtv[j] = dts[s0 + kq + j]; }
      short8 bfr[4];
#pragma unroll
      for (int j = 0; j < 4; ++j)
        bfr[j] = *(const short8*)&Xb[j*16 + fr][kq];
#pragma unroll
      for (int i = 0; i < 4; ++i) {
        int t = wt0 + i*16 + fr;
        const float* cbrow = CBs + cbbase + (size_t)t*CHUNK + s0 + kq;
        float4 c0 = *(const float4*)cbrow;
        float4 c1 = *(const float4*)(cbrow + 4);
        float cb[8] = {c0.x,c0.y,c0.z,c0.w,c1.x,c1.y,c1.z,c1.w};
        short8 af;
#pragma unroll
        for (int j = 0; j < 8; ++j) {
          int s = s0 + kq + j;
          float wv = (s <= t) ? cb[j] * __expf(ct[i] - cs[j]) * dtv[j] : 0.f;
          af[j] = (short)f2bf(wv);
        }
#pragma unroll
        for (int j = 0; j < 4; ++j)
          acc[i][j] = __builtin_amdgcn_mfma_f32_16x16x32_bf16(af, bfr[j], acc[i][j], 0, 0, 0);
      }
    }
  }
  if (r < 2) {
    float ect[4];
#pragma unroll
    for (int i = 0; i < 4; ++i) ect[i] = __expf(ct[i]);
    const float* spbase = SPREV + (((size_t)r*NCH + c)*NHEADS + h) * (size_t)(HEADDIM*D_STATE);
#pragma unroll
    for (int ns = 0; ns < 2; ++ns) {
      int n0 = ns * 32;
      short8 bfr[4];
#pragma unroll
      for (int j = 0; j < 4; ++j) {
        const float* sp = spbase + (size_t)(j*16 + fr)*D_STATE + n0 + kq;
        float4 s0v = *(const float4*)sp;
        float4 s1v = *(const float4*)(sp + 4);
        short8 bb;
        bb[0]=(short)f2bf(s0v.x); bb[1]=(short)f2bf(s0v.y); bb[2]=(short)f2bf(s0v.z); bb[3]=(short)f2bf(s0v.w);
        bb[4]=(short)f2bf(s1v.x); bb[5]=(short)f2bf(s1v.y); bb[6]=(short)f2bf(s1v.z); bb[7]=(short)f2bf(s1v.w);
        bfr[j] = bb;
      }
#pragma unroll
      for (int i = 0; i < 4; ++i) {
        int t = wt0 + i*16 + fr;
        const unsigned short* crow = XTb + ((size_t)bi*SEQLEN + c*CHUNK + t)*CONV_DIM + D_INNER + GN + n0 + kq;
        ushort4 c0 = *(const ushort4*)crow;
        ushort4 c1 = *(const ushort4*)(crow + 4);
        short8 af;
        af[0]=(short)f2bf(bf2f(c0.x)*ect[i]); af[1]=(short)f2bf(bf2f(c0.y)*ect[i]);
        af[2]=(short)f2bf(bf2f(c0.z)*ect[i]); af[3]=(short)f2bf(bf2f(c0.w)*ect[i]);
        af[4]=(short)f2bf(bf2f(c1.x)*ect[i]); af[5]=(short)f2bf(bf2f(c1.y)*ect[i]);
        af[6]=(short)f2bf(bf2f(c1.z)*ect[i]); af[7]=(short)f2bf(bf2f(c1.w)*ect[i]);
#pragma unroll
        for (int j = 0; j < 4; ++j)
          acc[i][j] = __builtin_amdgcn_mfma_f32_16x16x32_bf16(af, bfr[j], acc[i][j], 0, 0, 0);
      }
    }
  }
  const int rg = (lane >> 4) * 4;
  size_t ybase = ((size_t)r*SEQLEN + c*CHUNK)*D_INNER + h*HEADDIM;
#pragma unroll
  for (int i = 0; i < 4; ++i)
#pragma unroll
    for (int j = 0; j < 4; ++j)
#pragma unroll
      for (int q = 0; q < 4; ++q)
        Y[ybase + (size_t)(wt0 + i*16 + rg + q)*D_INNER + j*16 + fr] = acc[i][j][q];
}

// ---------------- shifts + x_res + RMSNorm + gate (vectorized, -> bf16) ----------------
__global__ __launch_bounds__(256) void combine_kernel(const float* __restrict__ Y,
                                                      const unsigned short* __restrict__ XTb,
                                                      const float* __restrict__ FCD,
                                                      const float* __restrict__ Dp,
                                                      const unsigned short* __restrict__ Zb,
                                                      const float* __restrict__ norm_w,
                                                      unsigned short* __restrict__ YPb) {
  __shared__ float red[256];
  int row = blockIdx.x;
  int bi = row >> 11;
  int l = row & 2047;
  int s = l >> 3, fr = l & 7;
  int tid = threadIdx.x;
  int d0 = tid * 8;
  const float* yf = (l >= 1) ? Y + ((size_t)bi*SEQLEN + (l-1))*D_INNER + d0 : nullptr;
  const float* yr = (s >= 1) ? Y + ((size_t)(2+bi)*SEQLEN + ((s-1)*8 + (7-fr)))*D_INNER + d0 : nullptr;
  const unsigned short* xr = XTb + ((size_t)row)*CONV_DIM + d0;
  float fcv = FCD[(size_t)row*NHEADS + (d0 >> 6)] + Dp[d0 >> 6];
  ushort8v xv8 = *(const ushort8v*)xr;
  float v[8];
#pragma unroll
  for (int q = 0; q < 8; ++q) v[q] = bf2f(xv8[q]) * fcv;
  if (yf) {
    float4 a = *(const float4*)yf, b = *(const float4*)(yf + 4);
    v[0]+=a.x; v[1]+=a.y; v[2]+=a.z; v[3]+=a.w;
    v[4]+=b.x; v[5]+=b.y; v[6]+=b.z; v[7]+=b.w;
  }
  if (yr) {
    float4 a = *(const float4*)yr, b = *(const float4*)(yr + 4);
    v[0]+=a.x; v[1]+=a.y; v[2]+=a.z; v[3]+=a.w;
    v[4]+=b.x; v[5]+=b.y; v[6]+=b.z; v[7]+=b.w;
  }
  float ss = 0.f;
#pragma unroll
  for (int q = 0; q < 8; ++q) ss += v[q] * v[q];
  red[tid] = ss;
  __syncthreads();
  for (int ofs = 128; ofs > 0; ofs >>= 1) {
    if (tid < ofs) red[tid] += red[tid + ofs];
    __syncthreads();
  }
  float rs = rsqrtf(red[0] / (float)D_INNER + 1e-5f);
  ushort8v zv8 = *(const ushort8v*)(Zb + ((size_t)row)*ZLD + d0);
  float4 nw0 = *(const float4*)(norm_w + d0);
  float4 nw1 = *(const float4*)(norm_w + d0 + 4);
  float nw[8] = {nw0.x,nw0.y,nw0.z,nw0.w,nw1.x,nw1.y,nw1.z,nw1.w};
  ushort8v o;
#pragma unroll
  for (int q = 0; q < 8; ++q)
    o[q] = f2bf(v[q] * rs * nw[q] * silu_f(bf2f(zv8[q])));
  *(ushort8v*)(YPb + (size_t)row*D_INNER + d0) = o;
}

extern "C" void kernel_launch(void* const* d_in, const int* in_sizes, int n_in,
                              void* d_out, int out_size, void* d_ws, size_t ws_size,
                              hipStream_t stream) {
  (void)in_sizes; (void)n_in; (void)out_size; (void)ws_size;
  const float* u          = (const float*)d_in[0];
  const float* in_proj_w  = (const float*)d_in[1];
  const float* conv_sp_w  = (const float*)d_in[2];
  const float* conv_sp_b  = (const float*)d_in[3];
  const float* conv_tp_w  = (const float*)d_in[4];
  const float* conv_tp_b  = (const float*)d_in[5];
  const float* dt_bias    = (const float*)d_in[6];
  const float* A_log      = (const float*)d_in[7];
  const float* Dp         = (const float*)d_in[8];
  const float* fc_D_w     = (const float*)d_in[9];
  const float* norm_w     = (const float*)d_in[10];
  const float* out_proj_w = (const float*)d_in[11];
  float* out = (float*)d_out;
  float* ws = (float*)d_ws;

  // workspace layout (f32-element offsets; Z/XT regions hold bf16)
  float* Z     = ws;                       // 17,825,792 slots (bf16 uses half)
  float* SH    = Z     + 17825792ULL;      // 9,437,184  (CBs -> YPb)
  float* XT    = SH    + 9437184ULL;       // 9,437,184  (bf16 uses half)
  float* DTt   = XT    + 9437184ULL;       // 262,144
  float* Yb    = DTt   + 262144ULL;        // 16,777,216 (hosts bf16 staging + SCH early)
  float* SPREV = Yb    + 16777216ULL;      // 2,097,152
  float* FCD   = SPREV + 2097152ULL;       // 131,072
  float* DTraw = FCD   + 131072ULL;        // 262,144
  float* CUMS  = DTraw + 262144ULL;        // 262,144

  unsigned short* Zb  = (unsigned short*)Z;
  unsigned short* XTb = (unsigned short*)XT;
  unsigned short* Ub  = (unsigned short*)Yb;
  unsigned short* Wb  = (unsigned short*)Yb + 4194304ULL;
  float* SCH = Yb + 8388608ULL;            // 2,097,152 (dead before yscan writes Yb)
  unsigned short* Wob = (unsigned short*)Yb;
  unsigned short* YPb = (unsigned short*)SH;

  cast2_bf16_kernel<<<8448, 256, 0, stream>>>(u, Ub, 4096, in_proj_w, Wb);
  gemm_bf16_bf16out<<<1088, 256, 0, stream>>>(Ub, 1024, Wb, 1024, Zb, ZLD, 1024, 34, 32);
  gemm_skinny_f32<<<256, 256, 0, stream>>>(u, 1024, in_proj_w + 4352ULL*1024, 1024,
                                           DTraw, 64, 64, 1024);
  dtscan_kernel<<<1024, 256, 0, stream>>>(DTraw, dt_bias, A_log, DTt, CUMS);
  conv_fused2_kernel<<<dim3(18, 32, 2), 256, 0, stream>>>(Zb, conv_sp_w, conv_sp_b,
                                                          conv_tp_w, conv_tp_b, XTb);
  gemm_skinny_a16<<<256, 256, 0, stream>>>(XTb, 2304, fc_D_w, 2048, FCD, 32, 32, 2048);
  cb_kernel<<<dim3(16, 8, 4), 256, 0, stream>>>(XTb, SH);
  chunk_state_kernel<<<dim3(NCH, NHEADS, 2), 256, 0, stream>>>(XTb, DTt, CUMS, SCH);
  state_combine_kernel<<<256, 256, 0, stream>>>(SCH, CUMS, SPREV);
  yscan_kernel<<<dim3(8, 128), 256, 0, stream>>>(XTb, DTt, CUMS, SH, SPREV, Yb);
  combine_kernel<<<4096, 256, 0, stream>>>(Yb, XTb, FCD, Dp, Zb, norm_w, YPb);
  cast_bf16_kernel<<<2048, 256, 0, stream>>>(out_proj_w, Wob);
  gemm_bf16<<<256, 256, 0, stream>>>(YPb, 2048, Wob, 2048, out, 1024, 2048, 8, 32);
}

// Round 9
// 437.867 us; speedup vs baseline: 1.0182x; 1.0182x over previous
//
#include <hip/hip_runtime.h>
#include <hip/hip_bf16.h>
#include <math.h>

#define D_STATE   64
#define HEADDIM   64
#define D_INNER   2048
#define NHEADS    32
#define GN        64
#define CONV_DIM  2304
#define D_IN_PROJ 4416
#define ZLD       4352      /* z + xBC columns only (dt handled separately) */
#define K_SP      7
#define K_TP      4
#define CHUNK     256
#define BATCHN    2
#define FRAMES    8
#define SPATIAL   256
#define SEQLEN    2048
#define NCH       8
#define MTOT      4096

typedef __attribute__((ext_vector_type(8))) short short8;
typedef __attribute__((ext_vector_type(8))) unsigned short ushort8v;
typedef __attribute__((ext_vector_type(4))) float floatx4;

__device__ __forceinline__ float silu_f(float x) { return x / (1.f + __expf(-x)); }
__device__ __forceinline__ int flip_l(int l) { return (l & ~7) | (7 - (l & 7)); }
__device__ __forceinline__ unsigned short f2bf(float f) {
  unsigned int u = __float_as_uint(f);
  unsigned int r = (u + 0x7fffu + ((u >> 16) & 1u)) >> 16;
  return (unsigned short)r;
}
__device__ __forceinline__ float bf2f(unsigned short s) {
  return __uint_as_float(((unsigned int)s) << 16);
}
__device__ __forceinline__ void gload_lds16(const unsigned short* g, unsigned short* l) {
  __builtin_amdgcn_global_load_lds((const __attribute__((address_space(1))) void*)g,
                                   (__attribute__((address_space(3))) void*)l, 16, 0, 0);
}

// ---------------- f32 -> bf16 cast (two tensors, one launch) ----------------
__global__ __launch_bounds__(256) void cast2_bf16_kernel(const float* __restrict__ a,
                                                         unsigned short* __restrict__ oa,
                                                         int na_blocks,
                                                         const float* __restrict__ b,
                                                         unsigned short* __restrict__ ob) {
  int bid = blockIdx.x;
  const float* in;
  unsigned short* out;
  size_t i;
  if (bid < na_blocks) {
    in = a; out = oa;
    i = ((size_t)bid * 256 + threadIdx.x) * 4;
  } else {
    in = b; out = ob;
    i = ((size_t)(bid - na_blocks) * 256 + threadIdx.x) * 4;
  }
  float4 v = *(const float4*)(in + i);
  ushort4 o;
  o.x = f2bf(v.x); o.y = f2bf(v.y); o.z = f2bf(v.z); o.w = f2bf(v.w);
  *(ushort4*)(out + i) = o;
}

__global__ __launch_bounds__(256) void cast_bf16_kernel(const float* __restrict__ in,
                                                        unsigned short* __restrict__ out) {
  size_t i = ((size_t)blockIdx.x * 256 + threadIdx.x) * 4;
  float4 v = *(const float4*)(in + i);
  ushort4 o;
  o.x = f2bf(v.x); o.y = f2bf(v.y); o.z = f2bf(v.z); o.w = f2bf(v.w);
  *(ushort4*)(out + i) = o;
}

// ---------------- bf16 MFMA GEMM (f32 out): C = A * B^T ----------------
__global__ __launch_bounds__(256) void gemm_bf16(
    const unsigned short* __restrict__ A, int lda,
    const unsigned short* __restrict__ B, int ldb,
    float* __restrict__ C, int ldc, int K) {
  __shared__ unsigned short As[128 * 32];
  __shared__ unsigned short Bs[128 * 32];
  const int tid = threadIdx.x;
  const int lane = tid & 63;
  const int w = tid >> 6;
  const int m0 = blockIdx.y * 128;
  const int n0 = blockIdx.x * 128;
  const int wm = (w >> 1) * 64;
  const int wn = (w & 1) * 64;
  const int srow = lane >> 2;
  const int scol = (lane & 3) * 8;
  floatx4 acc[4][4] = {};
  for (int k0 = 0; k0 < K; k0 += 32) {
#pragma unroll
    for (int it = 0; it < 2; ++it) {
      int ch = it * 4 + w;
      gload_lds16(A + (size_t)(m0 + ch * 16 + srow) * lda + k0 + scol, &As[ch * 512]);
      gload_lds16(B + (size_t)(n0 + ch * 16 + srow) * ldb + k0 + scol, &Bs[ch * 512]);
    }
    __syncthreads();
    const int fr = lane & 15;
    const int kq = (lane >> 4) * 8;
    short8 af[4], bfr[4];
#pragma unroll
    for (int i = 0; i < 4; ++i)
      af[i] = *(const short8*)&As[(wm + i * 16 + fr) * 32 + kq];
#pragma unroll
    for (int j = 0; j < 4; ++j)
      bfr[j] = *(const short8*)&Bs[(wn + j * 16 + fr) * 32 + kq];
#pragma unroll
    for (int i = 0; i < 4; ++i)
#pragma unroll
      for (int j = 0; j < 4; ++j)
        acc[i][j] = __builtin_amdgcn_mfma_f32_16x16x32_bf16(af[i], bfr[j], acc[i][j], 0, 0, 0);
    __syncthreads();
  }
  const int col = lane & 15;
  const int rg = (lane >> 4) * 4;
#pragma unroll
  for (int i = 0; i < 4; ++i)
#pragma unroll
    for (int j = 0; j < 4; ++j)
#pragma unroll
      for (int r = 0; r < 4; ++r)
        C[(size_t)(m0 + wm + i * 16 + rg + r) * ldc + (n0 + wn + j * 16 + col)] = acc[i][j][r];
}

// ---------------- bf16 MFMA GEMM (bf16 out, vectorized epilogue) ----------------
__global__ __launch_bounds__(256) void gemm_bf16_bf16out(
    const unsigned short* __restrict__ A, int lda,
    const unsigned short* __restrict__ B, int ldb,
    unsigned short* __restrict__ C, int ldc, int K) {
  __shared__ unsigned short As[128 * 32];
  __shared__ unsigned short Bs[128 * 32];
  const int tid = threadIdx.x;
  const int lane = tid & 63;
  const int w = tid >> 6;
  const int m0 = blockIdx.y * 128;
  const int n0 = blockIdx.x * 128;
  const int wm = (w >> 1) * 64;
  const int wn = (w & 1) * 64;
  const int srow = lane >> 2;
  const int scol = (lane & 3) * 8;
  floatx4 acc[4][4] = {};
  for (int k0 = 0; k0 < K; k0 += 32) {
#pragma unroll
    for (int it = 0; it < 2; ++it) {
      int ch = it * 4 + w;
      gload_lds16(A + (size_t)(m0 + ch * 16 + srow) * lda + k0 + scol, &As[ch * 512]);
      gload_lds16(B + (size_t)(n0 + ch * 16 + srow) * ldb + k0 + scol, &Bs[ch * 512]);
    }
    __syncthreads();
    const int fr = lane & 15;
    const int kq = (lane >> 4) * 8;
    short8 af[4], bfr[4];
#pragma unroll
    for (int i = 0; i < 4; ++i)
      af[i] = *(const short8*)&As[(wm + i * 16 + fr) * 32 + kq];
#pragma unroll
    for (int j = 0; j < 4; ++j)
      bfr[j] = *(const short8*)&Bs[(wn + j * 16 + fr) * 32 + kq];
#pragma unroll
    for (int i = 0; i < 4; ++i)
#pragma unroll
      for (int j = 0; j < 4; ++j)
        acc[i][j] = __builtin_amdgcn_mfma_f32_16x16x32_bf16(af[i], bfr[j], acc[i][j], 0, 0, 0);
    __syncthreads();
  }
  // epilogue: per-wave LDS transpose (reuse As), ushort8 coalesced stores
  const int fr = lane & 15;
  const int rg = (lane >> 4) * 4;
  unsigned short* Ew = &As[w * 1024];
  const int rr = lane >> 3;
  const int c8 = (lane & 7) * 8;
#pragma unroll
  for (int i = 0; i < 4; ++i) {
#pragma unroll
    for (int q = 0; q < 4; ++q)
#pragma unroll
      for (int j = 0; j < 4; ++j)
        Ew[(rg + q) * 64 + j * 16 + fr] = f2bf(acc[i][j][q]);
    ushort8v v0 = *(const ushort8v*)&Ew[rr * 64 + c8];
    ushort8v v1 = *(const ushort8v*)&Ew[(rr + 8) * 64 + c8];
    *(ushort8v*)(C + (size_t)(m0 + wm + i * 16 + rr) * ldc + n0 + wn + c8) = v0;
    *(ushort8v*)(C + (size_t)(m0 + wm + i * 16 + rr + 8) * ldc + n0 + wn + c8) = v1;
  }
}

// ---------------- skinny f32 GEMM: C[M x N(<=64)] = A * B^T, M-tile=16 ----------------
__global__ __launch_bounds__(256) void gemm_skinny_f32(
    const float* __restrict__ A, int lda,
    const float* __restrict__ B, int ldb,
    float* __restrict__ C, int ldc, int N, int K) {
  __shared__ float Bs[64][68];
  __shared__ float As[16][68];
  const int tid = threadIdx.x;
  const int m0 = blockIdx.x * 16;
  const int tm = tid >> 4;
  const int tn4 = (tid & 15) * 4;
  float acc[4] = {0.f, 0.f, 0.f, 0.f};
  for (int k0 = 0; k0 < K; k0 += 64) {
    __syncthreads();
    {
      int bn = tid >> 2;
      int bk = (tid & 3) * 16;
      if (bn < N) {
#pragma unroll
        for (int q = 0; q < 4; ++q) {
          float4 v = *(const float4*)(B + (size_t)bn * ldb + k0 + bk + q * 4);
          Bs[bk + q*4 + 0][bn] = v.x;
          Bs[bk + q*4 + 1][bn] = v.y;
          Bs[bk + q*4 + 2][bn] = v.z;
          Bs[bk + q*4 + 3][bn] = v.w;
        }
      } else {
#pragma unroll
        for (int q = 0; q < 4; ++q) {
          Bs[bk + q*4 + 0][bn] = 0.f;
          Bs[bk + q*4 + 1][bn] = 0.f;
          Bs[bk + q*4 + 2][bn] = 0.f;
          Bs[bk + q*4 + 3][bn] = 0.f;
        }
      }
      int am = tid >> 4;
      int ak = (tid & 15) * 4;
      *(float4*)&As[am][ak] = *(const float4*)(A + (size_t)(m0 + am) * lda + k0 + ak);
    }
    __syncthreads();
#pragma unroll 8
    for (int k = 0; k < 64; ++k) {
      float a = As[tm][k];
      float4 b4 = *(const float4*)&Bs[k][tn4];
      acc[0] += a * b4.x; acc[1] += a * b4.y;
      acc[2] += a * b4.z; acc[3] += a * b4.w;
    }
  }
  if (tn4 < N)
    *(float4*)(C + (size_t)(m0 + tm) * ldc + tn4) = make_float4(acc[0], acc[1], acc[2], acc[3]);
}

// ---------------- skinny GEMM, bf16 A: C[M x N(<=64)] = A * B^T ----------------
__global__ __launch_bounds__(256) void gemm_skinny_a16(
    const unsigned short* __restrict__ A, int lda,
    const float* __restrict__ B, int ldb,
    float* __restrict__ C, int ldc, int N, int K) {
  __shared__ float Bs[64][68];
  __shared__ float As[16][68];
  const int tid = threadIdx.x;
  const int m0 = blockIdx.x * 16;
  const int tm = tid >> 4;
  const int tn4 = (tid & 15) * 4;
  float acc[4] = {0.f, 0.f, 0.f, 0.f};
  for (int k0 = 0; k0 < K; k0 += 64) {
    __syncthreads();
    {
      int bn = tid >> 2;
      int bk = (tid & 3) * 16;
      if (bn < N) {
#pragma unroll
        for (int q = 0; q < 4; ++q) {
          float4 v = *(const float4*)(B + (size_t)bn * ldb + k0 + bk + q * 4);
          Bs[bk + q*4 + 0][bn] = v.x;
          Bs[bk + q*4 + 1][bn] = v.y;
          Bs[bk + q*4 + 2][bn] = v.z;
          Bs[bk + q*4 + 3][bn] = v.w;
        }
      } else {
#pragma unroll
        for (int q = 0; q < 4; ++q) {
          Bs[bk + q*4 + 0][bn] = 0.f;
          Bs[bk + q*4 + 1][bn] = 0.f;
          Bs[bk + q*4 + 2][bn] = 0.f;
          Bs[bk + q*4 + 3][bn] = 0.f;
        }
      }
      int am = tid >> 4;
      int ak = (tid & 15) * 4;
      ushort4 v = *(const ushort4*)(A + (size_t)(m0 + am) * lda + k0 + ak);
      As[am][ak+0] = bf2f(v.x); As[am][ak+1] = bf2f(v.y);
      As[am][ak+2] = bf2f(v.z); As[am][ak+3] = bf2f(v.w);
    }
    __syncthreads();
#pragma unroll 8
    for (int k = 0; k < 64; ++k) {
      float a = As[tm][k];
      float4 b4 = *(const float4*)&Bs[k][tn4];
      acc[0] += a * b4.x; acc[1] += a * b4.y;
      acc[2] += a * b4.z; acc[3] += a * b4.w;
    }
  }
  if (tn4 < N)
    *(float4*)(C + (size_t)(m0 + tm) * ldc + tn4) = make_float4(acc[0], acc[1], acc[2], acc[3]);
}

// ---------------- dt = softplus(dt_raw + bias), flip for reverse; + chunk-local cumsum ----------------
__global__ __launch_bounds__(256) void dtscan_kernel(const float* __restrict__ DTraw,
                                                     const float* __restrict__ dt_bias,
                                                     const float* __restrict__ A_log,
                                                     float* __restrict__ DTt,
                                                     float* __restrict__ CUMS) {
  __shared__ float sc[256];
  int tid = threadIdx.x;
  int idx = blockIdx.x * 256 + tid;
  int l  = idx & 2047;
  int rh = idx >> 11;
  int h  = rh & 31;
  int r  = rh >> 5;
  int bi = r & 1;
  int ls = (r < 2) ? l : flip_l(l);
  int ch = (r < 2) ? h : NHEADS + h;
  float raw = DTraw[((size_t)bi * SEQLEN + ls) * 64 + ch] + dt_bias[h];
  float dtv = (raw > 20.f) ? raw : log1pf(__expf(raw));
  DTt[idx] = dtv;
  float A = -__expf(A_log[h]);
  float run = dtv * A;
  sc[tid] = run;
  __syncthreads();
#pragma unroll
  for (int ofs = 1; ofs < 256; ofs <<= 1) {
    float add = (tid >= ofs) ? sc[tid - ofs] : 0.f;
    __syncthreads();
    run += add;
    sc[tid] = run;
    __syncthreads();
  }
  CUMS[idx] = run;
}

// ---------------- fused convs: bf16 in/out, register sliding-window ----------------
__global__ __launch_bounds__(256) void conv_fused2_kernel(const unsigned short* __restrict__ Zb,
                                                          const float* __restrict__ wsp,
                                                          const float* __restrict__ bsp,
                                                          const float* __restrict__ wtp,
                                                          const float* __restrict__ btp,
                                                          unsigned short* __restrict__ XTb) {
  __shared__ float4 xsl[8][8][32];
  const int tid = threadIdx.x;
  const int g  = tid & 31;
  const int fr = tid >> 5;
  const int c  = blockIdx.x * 128 + g * 4;
  const int s0 = blockIdx.y * 8;
  const int bi = blockIdx.z;
  float wsp_r[4][K_SP];
#pragma unroll
  for (int ch = 0; ch < 4; ++ch)
#pragma unroll
    for (int j = 0; j < K_SP; ++j) wsp_r[ch][j] = wsp[(c + ch) * K_SP + j];
  float4 bsp4 = *(const float4*)(bsp + c);
  float4 z[14];
#pragma unroll
  for (int i = 0; i < 14; ++i) {
    int ss = s0 - 3 + i;
    if (0 <= ss && ss < SPATIAL) {
      ushort4 v = *(const ushort4*)(Zb + ((size_t)bi * SEQLEN + (ss*8 + fr)) * ZLD + D_INNER + c);
      z[i] = make_float4(bf2f(v.x), bf2f(v.y), bf2f(v.z), bf2f(v.w));
    } else {
      z[i] = make_float4(0.f, 0.f, 0.f, 0.f);
    }
  }
#pragma unroll
  for (int so = 0; so < 8; ++so) {
    float4 a = bsp4;
#pragma unroll
    for (int j = 0; j < K_SP; ++j) {
      a.x += wsp_r[0][j] * z[so + j].x;
      a.y += wsp_r[1][j] * z[so + j].y;
      a.z += wsp_r[2][j] * z[so + j].z;
      a.w += wsp_r[3][j] * z[so + j].w;
    }
    a.x = silu_f(a.x); a.y = silu_f(a.y); a.z = silu_f(a.z); a.w = silu_f(a.w);
    xsl[fr][so][g] = a;
  }
  __syncthreads();
  float wtp_r[4][K_TP];
#pragma unroll
  for (int ch = 0; ch < 4; ++ch)
#pragma unroll
    for (int j = 0; j < K_TP; ++j) wtp_r[ch][j] = wtp[(c + ch) * K_TP + j];
  float4 btp4 = *(const float4*)(btp + c);
#pragma unroll
  for (int so = 0; so < 8; ++so) {
    float4 t = btp4;
#pragma unroll
    for (int j = 0; j < K_TP; ++j) {
      int ff = fr + j - (K_TP - 1);
      if (ff >= 0) {
        float4 xv = xsl[ff][so][g];
        t.x += wtp_r[0][j] * xv.x;
        t.y += wtp_r[1][j] * xv.y;
        t.z += wtp_r[2][j] * xv.z;
        t.w += wtp_r[3][j] * xv.w;
      }
    }
    ushort4 o;
    o.x = f2bf(silu_f(t.x)); o.y = f2bf(silu_f(t.y));
    o.z = f2bf(silu_f(t.z)); o.w = f2bf(silu_f(t.w));
    *(ushort4*)(XTb + ((size_t)bi * SEQLEN + ((s0 + so)*8 + fr)) * CONV_DIM + c) = o;
  }
}

// ---------------- CB[t][s] = sum_n C[t][n] B[s][n], per (r,c)  (t-major) ----------------
__global__ __launch_bounds__(256) void cb_kernel(const unsigned short* __restrict__ XTb,
                                                 float* __restrict__ CBs) {
  __shared__ float Ct[64][65];
  __shared__ float Bt[64][65];
  int tid = threadIdx.x;
  int t0 = (blockIdx.x & 3) * 64;
  int s0 = (blockIdx.x >> 2) * 64;
  if (s0 > t0) return;
  int c = blockIdx.y;
  int r = blockIdx.z;
  int bi = r & 1;
  int bOff = D_INNER + ((r < 2) ? 0 : 2*GN);
  int cOff = bOff + GN;
  int lrow = tid >> 4;
  int n4 = (tid & 15) << 2;
#pragma unroll
  for (int rep = 0; rep < 4; ++rep) {
    int tl = rep * 16 + lrow;
    int Lc = c * CHUNK + t0 + tl;
    int Ls = c * CHUNK + s0 + tl;
    if (r >= 2) { Lc = flip_l(Lc); Ls = flip_l(Ls); }
    ushort4 cv = *(const ushort4*)(XTb + ((size_t)bi*SEQLEN + Lc)*CONV_DIM + cOff + n4);
    ushort4 bv = *(const ushort4*)(XTb + ((size_t)bi*SEQLEN + Ls)*CONV_DIM + bOff + n4);
    Ct[n4+0][tl] = bf2f(cv.x); Ct[n4+1][tl] = bf2f(cv.y);
    Ct[n4+2][tl] = bf2f(cv.z); Ct[n4+3][tl] = bf2f(cv.w);
    Bt[n4+0][tl] = bf2f(bv.x); Bt[n4+1][tl] = bf2f(bv.y);
    Bt[n4+2][tl] = bf2f(bv.z); Bt[n4+3][tl] = bf2f(bv.w);
  }
  __syncthreads();
  int txx = tid & 15;
  int tyy = tid >> 4;
  float acc[4][4] = {{0.f,0.f,0.f,0.f},{0.f,0.f,0.f,0.f},{0.f,0.f,0.f,0.f},{0.f,0.f,0.f,0.f}};
#pragma unroll
  for (int n = 0; n < D_STATE; ++n) {
    float cr[4], br[4];
#pragma unroll
    for (int i = 0; i < 4; ++i) cr[i] = Ct[n][tyy + 16*i];
#pragma unroll
    for (int j = 0; j < 4; ++j) br[j] = Bt[n][txx + 16*j];
#pragma unroll
    for (int i = 0; i < 4; ++i)
#pragma unroll
      for (int j = 0; j < 4; ++j)
        acc[i][j] += cr[i] * br[j];
  }
  size_t base = (((size_t)r*NCH + c) * CHUNK) * CHUNK;
#pragma unroll
  for (int i = 0; i < 4; ++i)
#pragma unroll
    for (int j = 0; j < 4; ++j)
      CBs[base + (size_t)(t0 + tyy + 16*i)*CHUNK + (s0 + txx + 16*j)] = acc[i][j];
}

// ---------------- per-chunk state sums (MFMA, forward r=0,1 only) ----------------
__global__ __launch_bounds__(256) void chunk_state_kernel(const unsigned short* __restrict__ XTb,
                                                          const float* __restrict__ DTt,
                                                          const float* __restrict__ CUMS,
                                                          float* __restrict__ SCH) {
  __shared__ unsigned short Xb[64][40];
  __shared__ unsigned short Bb[64][40];
  int tid = threadIdx.x;
  int lane = tid & 63;
  int w = tid >> 6;
  int c = blockIdx.x;
  int h = blockIdx.y;
  int r = blockIdx.z;
  int bi = r;
  int rh = r * NHEADS + h;
  float cl = CUMS[(size_t)rh*SEQLEN + c*CHUNK + 255];
  const int fr = lane & 15;
  const int kq = (lane >> 4) * 8;
  floatx4 acc[4] = {};
  for (int sl = 0; sl < 8; ++sl) {
    int s0 = sl * 32;
    __syncthreads();
    {
      int srow = tid >> 3;
      int cg = (tid & 7) * 8;
      int l = c*CHUNK + s0 + srow;
      float g = __expf(cl - CUMS[(size_t)rh*SEQLEN + l]) * DTt[(size_t)rh*SEQLEN + l];
      const unsigned short* row = XTb + ((size_t)bi*SEQLEN + l)*CONV_DIM;
      ushort4 x0 = *(const ushort4*)(row + h*HEADDIM + cg);
      ushort4 x1 = *(const ushort4*)(row + h*HEADDIM + cg + 4);
      ushort4 b0 = *(const ushort4*)(row + D_INNER + cg);
      ushort4 b1 = *(const ushort4*)(row + D_INNER + cg + 4);
      Xb[cg+0][srow] = f2bf(g*bf2f(x0.x)); Xb[cg+1][srow] = f2bf(g*bf2f(x0.y));
      Xb[cg+2][srow] = f2bf(g*bf2f(x0.z)); Xb[cg+3][srow] = f2bf(g*bf2f(x0.w));
      Xb[cg+4][srow] = f2bf(g*bf2f(x1.x)); Xb[cg+5][srow] = f2bf(g*bf2f(x1.y));
      Xb[cg+6][srow] = f2bf(g*bf2f(x1.z)); Xb[cg+7][srow] = f2bf(g*bf2f(x1.w));
      Bb[cg+0][srow] = b0.x; Bb[cg+1][srow] = b0.y;
      Bb[cg+2][srow] = b0.z; Bb[cg+3][srow] = b0.w;
      Bb[cg+4][srow] = b1.x; Bb[cg+5][srow] = b1.y;
      Bb[cg+6][srow] = b1.z; Bb[cg+7][srow] = b1.w;
    }
    __syncthreads();
    short8 af = *(const short8*)&Xb[w*16 + fr][kq];
#pragma unroll
    for (int j = 0; j < 4; ++j) {
      short8 bf8 = *(const short8*)&Bb[j*16 + fr][kq];
      acc[j] = __builtin_amdgcn_mfma_f32_16x16x32_bf16(af, bf8, acc[j], 0, 0, 0);
    }
  }
  const int col = lane & 15;
  const int rg = (lane >> 4) * 4;
  size_t base = (((size_t)r*NCH + c)*NHEADS + h) * (size_t)(HEADDIM*D_STATE);
#pragma unroll
  for (int j = 0; j < 4; ++j)
#pragma unroll
    for (int q = 0; q < 4; ++q)
      SCH[base + (size_t)(w*16 + rg + q)*D_STATE + j*16 + col] = acc[j][q];
}

// ---------------- prefix-combine chunk states -> SPREV ----------------
__global__ __launch_bounds__(256) void state_combine_kernel(const float* __restrict__ SCH,
                                                            const float* __restrict__ CUMS,
                                                            float* __restrict__ SPREV) {
  int bid = blockIdx.x;
  int pq = bid & 3;
  int h = (bid >> 2) & 31;
  int r = bid >> 7;
  int tid = threadIdx.x;
  int p = pq*16 + (tid >> 4);
  int n = (tid & 15) * 4;
  float4 S = make_float4(0.f, 0.f, 0.f, 0.f);
  for (int c = 0; c < NCH; ++c) {
    size_t off = ((((size_t)r*NCH + c)*NHEADS + h)*HEADDIM + p)*D_STATE + n;
    *(float4*)(SPREV + off) = S;
    float dec = __expf(CUMS[((size_t)r*NHEADS + h)*SEQLEN + c*CHUNK + 255]);
    float4 v = *(const float4*)(SCH + off);
    S.x = dec*S.x + v.x; S.y = dec*S.y + v.y;
    S.z = dec*S.z + v.z; S.w = dec*S.w + v.w;
  }
}

// ---------------- Y = intra(triangular, MFMA) + inter (MFMA, fwd only), bf16 out ----------------
__global__ __launch_bounds__(256) void yscan_kernel(const unsigned short* __restrict__ XTb,
                                                    const float* __restrict__ DTt,
                                                    const float* __restrict__ CUMS,
                                                    const float* __restrict__ CBs,
                                                    const float* __restrict__ SPREV,
                                                    unsigned short* __restrict__ Yb16) {
  __shared__ unsigned short Xb[64][40];
  __shared__ float dts[CHUNK];
  __shared__ float cums[CHUNK];
  int tid = threadIdx.x;
  int lane = tid & 63;
  int w = tid >> 6;
  int c = blockIdx.x;
  int rh = blockIdx.y;
  int h = rh & 31;
  int r = rh >> 5;
  int bi = r & 1;
  dts[tid]  = DTt[(size_t)rh*SEQLEN + c*CHUNK + tid];
  cums[tid] = CUMS[(size_t)rh*SEQLEN + c*CHUNK + tid];
  __syncthreads();
  const int fr = lane & 15;
  const int kq = (lane >> 4) * 8;
  const int wt0 = w * 64;
  float ct[4];
#pragma unroll
  for (int i = 0; i < 4; ++i) ct[i] = cums[wt0 + i*16 + fr];
  floatx4 acc[4][4] = {};
  size_t cbbase = (((size_t)r*NCH + c) * CHUNK) * CHUNK;
  const int maxsl = 2*w + 1;
  for (int sl = 0; sl < 8; ++sl) {
    int s0 = sl * 32;
    __syncthreads();
    {
      int srow = tid >> 3;
      int p0 = (tid & 7) * 4;
      int L = c*CHUNK + s0 + srow;
      if (r >= 2) L = flip_l(L);
      const unsigned short* xrow = XTb + ((size_t)bi*SEQLEN + L)*CONV_DIM + h*HEADDIM;
#pragma unroll
      for (int half = 0; half < 2; ++half) {
        ushort4 v = *(const ushort4*)(xrow + p0 + half*32);
        Xb[p0 + half*32 + 0][srow] = v.x;
        Xb[p0 + half*32 + 1][srow] = v.y;
        Xb[p0 + half*32 + 2][srow] = v.z;
        Xb[p0 + half*32 + 3][srow] = v.w;
      }
    }
    __syncthreads();
    if (sl <= maxsl) {
      float cs[8], dtv[8];
#pragma unroll
      for (int j = 0; j < 8; ++j) { cs[j] = cums[s0 + kq + j]; dtv[j] = dts[s0 + kq + j]; }
      short8 bfr[4];
#pragma unroll
      for (int j = 0; j < 4; ++j)
        bfr[j] = *(const short8*)&Xb[j*16 + fr][kq];
#pragma unroll
      for (int i = 0; i < 4; ++i) {
        int t = wt0 + i*16 + fr;
        const float* cbrow = CBs + cbbase + (size_t)t*CHUNK + s0 + kq;
        float4 c0 = *(const float4*)cbrow;
        float4 c1 = *(const float4*)(cbrow + 4);
        float cb[8] = {c0.x,c0.y,c0.z,c0.w,c1.x,c1.y,c1.z,c1.w};
        short8 af;
#pragma unroll
        for (int j = 0; j < 8; ++j) {
          int s = s0 + kq + j;
          float wv = (s <= t) ? cb[j] * __expf(ct[i] - cs[j]) * dtv[j] : 0.f;
          af[j] = (short)f2bf(wv);
        }
#pragma unroll
        for (int j = 0; j < 4; ++j)
          acc[i][j] = __builtin_amdgcn_mfma_f32_16x16x32_bf16(af, bfr[j], acc[i][j], 0, 0, 0);
      }
    }
  }
  if (r < 2) {
    float ect[4];
#pragma unroll
    for (int i = 0; i < 4; ++i) ect[i] = __expf(ct[i]);
    const float* spbase = SPREV + (((size_t)r*NCH + c)*NHEADS + h) * (size_t)(HEADDIM*D_STATE);
#pragma unroll
    for (int ns = 0; ns < 2; ++ns) {
      int n0 = ns * 32;
      short8 bfr[4];
#pragma unroll
      for (int j = 0; j < 4; ++j) {
        const float* sp = spbase + (size_t)(j*16 + fr)*D_STATE + n0 + kq;
        float4 s0v = *(const float4*)sp;
        float4 s1v = *(const float4*)(sp + 4);
        short8 bb;
        bb[0]=(short)f2bf(s0v.x); bb[1]=(short)f2bf(s0v.y); bb[2]=(short)f2bf(s0v.z); bb[3]=(short)f2bf(s0v.w);
        bb[4]=(short)f2bf(s1v.x); bb[5]=(short)f2bf(s1v.y); bb[6]=(short)f2bf(s1v.z); bb[7]=(short)f2bf(s1v.w);
        bfr[j] = bb;
      }
#pragma unroll
      for (int i = 0; i < 4; ++i) {
        int t = wt0 + i*16 + fr;
        const unsigned short* crow = XTb + ((size_t)bi*SEQLEN + c*CHUNK + t)*CONV_DIM + D_INNER + GN + n0 + kq;
        ushort4 c0 = *(const ushort4*)crow;
        ushort4 c1 = *(const ushort4*)(crow + 4);
        short8 af;
        af[0]=(short)f2bf(bf2f(c0.x)*ect[i]); af[1]=(short)f2bf(bf2f(c0.y)*ect[i]);
        af[2]=(short)f2bf(bf2f(c0.z)*ect[i]); af[3]=(short)f2bf(bf2f(c0.w)*ect[i]);
        af[4]=(short)f2bf(bf2f(c1.x)*ect[i]); af[5]=(short)f2bf(bf2f(c1.y)*ect[i]);
        af[6]=(short)f2bf(bf2f(c1.z)*ect[i]); af[7]=(short)f2bf(bf2f(c1.w)*ect[i]);
#pragma unroll
        for (int j = 0; j < 4; ++j)
          acc[i][j] = __builtin_amdgcn_mfma_f32_16x16x32_bf16(af, bfr[j], acc[i][j], 0, 0, 0);
      }
    }
  }
  // bf16 epilogue: per-wave LDS transpose (reuse Xb; barrier — wave 0 races ahead)
  __syncthreads();
  unsigned short* Ew = (unsigned short*)Xb + w * 1024;
  const int rg = (lane >> 4) * 4;
  const int rr = lane >> 3;
  const int c8 = (lane & 7) * 8;
  size_t ybase = ((size_t)r*SEQLEN + c*CHUNK)*D_INNER + h*HEADDIM;
#pragma unroll
  for (int i = 0; i < 4; ++i) {
#pragma unroll
    for (int q = 0; q < 4; ++q)
#pragma unroll
      for (int j = 0; j < 4; ++j)
        Ew[(rg + q) * 64 + j * 16 + fr] = f2bf(acc[i][j][q]);
    ushort8v v0 = *(const ushort8v*)&Ew[rr * 64 + c8];
    ushort8v v1 = *(const ushort8v*)&Ew[(rr + 8) * 64 + c8];
    *(ushort8v*)(Yb16 + ybase + (size_t)(wt0 + i*16 + rr) * D_INNER + c8) = v0;
    *(ushort8v*)(Yb16 + ybase + (size_t)(wt0 + i*16 + rr + 8) * D_INNER + c8) = v1;
  }
}

// ---------------- shifts + x_res + RMSNorm + gate (vectorized, -> bf16) ----------------
__global__ __launch_bounds__(256) void combine_kernel(const unsigned short* __restrict__ Y,
                                                      const unsigned short* __restrict__ XTb,
                                                      const float* __restrict__ FCD,
                                                      const float* __restrict__ Dp,
                                                      const unsigned short* __restrict__ Zb,
                                                      const float* __restrict__ norm_w,
                                                      unsigned short* __restrict__ YPb) {
  __shared__ float red[256];
  int row = blockIdx.x;
  int bi = row >> 11;
  int l = row & 2047;
  int s = l >> 3, fr = l & 7;
  int tid = threadIdx.x;
  int d0 = tid * 8;
  const unsigned short* yf = (l >= 1) ? Y + ((size_t)bi*SEQLEN + (l-1))*D_INNER + d0 : nullptr;
  const unsigned short* yr = (s >= 1) ? Y + ((size_t)(2+bi)*SEQLEN + ((s-1)*8 + (7-fr)))*D_INNER + d0 : nullptr;
  const unsigned short* xr = XTb + ((size_t)row)*CONV_DIM + d0;
  float fcv = FCD[(size_t)row*NHEADS + (d0 >> 6)] + Dp[d0 >> 6];
  ushort8v xv8 = *(const ushort8v*)xr;
  float v[8];
#pragma unroll
  for (int q = 0; q < 8; ++q) v[q] = bf2f(xv8[q]) * fcv;
  if (yf) {
    ushort8v a = *(const ushort8v*)yf;
#pragma unroll
    for (int q = 0; q < 8; ++q) v[q] += bf2f(a[q]);
  }
  if (yr) {
    ushort8v a = *(const ushort8v*)yr;
#pragma unroll
    for (int q = 0; q < 8; ++q) v[q] += bf2f(a[q]);
  }
  float ss = 0.f;
#pragma unroll
  for (int q = 0; q < 8; ++q) ss += v[q] * v[q];
  red[tid] = ss;
  __syncthreads();
  for (int ofs = 128; ofs > 0; ofs >>= 1) {
    if (tid < ofs) red[tid] += red[tid + ofs];
    __syncthreads();
  }
  float rs = rsqrtf(red[0] / (float)D_INNER + 1e-5f);
  ushort8v zv8 = *(const ushort8v*)(Zb + ((size_t)row)*ZLD + d0);
  float4 nw0 = *(const float4*)(norm_w + d0);
  float4 nw1 = *(const float4*)(norm_w + d0 + 4);
  float nw[8] = {nw0.x,nw0.y,nw0.z,nw0.w,nw1.x,nw1.y,nw1.z,nw1.w};
  ushort8v o;
#pragma unroll
  for (int q = 0; q < 8; ++q)
    o[q] = f2bf(v[q] * rs * nw[q] * silu_f(bf2f(zv8[q])));
  *(ushort8v*)(YPb + (size_t)row*D_INNER + d0) = o;
}

extern "C" void kernel_launch(void* const* d_in, const int* in_sizes, int n_in,
                              void* d_out, int out_size, void* d_ws, size_t ws_size,
                              hipStream_t stream) {
  (void)in_sizes; (void)n_in; (void)out_size; (void)ws_size;
  const float* u          = (const float*)d_in[0];
  const float* in_proj_w  = (const float*)d_in[1];
  const float* conv_sp_w  = (const float*)d_in[2];
  const float* conv_sp_b  = (const float*)d_in[3];
  const float* conv_tp_w  = (const float*)d_in[4];
  const float* conv_tp_b  = (const float*)d_in[5];
  const float* dt_bias    = (const float*)d_in[6];
  const float* A_log      = (const float*)d_in[7];
  const float* Dp         = (const float*)d_in[8];
  const float* fc_D_w     = (const float*)d_in[9];
  const float* norm_w     = (const float*)d_in[10];
  const float* out_proj_w = (const float*)d_in[11];
  float* out = (float*)d_out;
  float* ws = (float*)d_ws;

  // workspace layout (f32-element offsets; Z/XT/Y regions hold bf16)
  float* Z     = ws;                       // 17,825,792 slots (bf16 uses half)
  float* SH    = Z     + 17825792ULL;      // 9,437,184  (CBs -> YPb)
  float* XT    = SH    + 9437184ULL;       // 9,437,184  (bf16 uses half)
  float* DTt   = XT    + 9437184ULL;       // 262,144
  float* Yb    = DTt   + 262144ULL;        // 16,777,216 (bf16 Y uses half; staging + SCH early)
  float* SPREV = Yb    + 16777216ULL;      // 2,097,152
  float* FCD   = SPREV + 2097152ULL;       // 131,072
  float* DTraw = FCD   + 131072ULL;        // 262,144
  float* CUMS  = DTraw + 262144ULL;        // 262,144

  unsigned short* Zb   = (unsigned short*)Z;
  unsigned short* XTb  = (unsigned short*)XT;
  unsigned short* Yb16 = (unsigned short*)Yb;            // 16,777,216 shorts (first 8,388,608 floats)
  unsigned short* Ub   = (unsigned short*)Yb;            // staging (dead before yscan)
  unsigned short* Wb   = (unsigned short*)Yb + 4194304ULL;
  float* SCH = Yb + 8388608ULL;            // 2,097,152 floats (disjoint from Yb16)
  unsigned short* Wob = (unsigned short*)SPREV;          // 2,097,152 shorts (SPREV dead after yscan)
  unsigned short* YPb = (unsigned short*)SH;

  cast2_bf16_kernel<<<8448, 256, 0, stream>>>(u, Ub, 4096, in_proj_w, Wb);
  gemm_bf16_bf16out<<<dim3(34, 32), 256, 0, stream>>>(Ub, 1024, Wb, 1024, Zb, ZLD, 1024);
  gemm_skinny_f32<<<256, 256, 0, stream>>>(u, 1024, in_proj_w + 4352ULL*1024, 1024,
                                           DTraw, 64, 64, 1024);
  dtscan_kernel<<<1024, 256, 0, stream>>>(DTraw, dt_bias, A_log, DTt, CUMS);
  conv_fused2_kernel<<<dim3(18, 32, 2), 256, 0, stream>>>(Zb, conv_sp_w, conv_sp_b,
                                                          conv_tp_w, conv_tp_b, XTb);
  gemm_skinny_a16<<<256, 256, 0, stream>>>(XTb, 2304, fc_D_w, 2048, FCD, 32, 32, 2048);
  cb_kernel<<<dim3(16, 8, 4), 256, 0, stream>>>(XTb, SH);
  chunk_state_kernel<<<dim3(NCH, NHEADS, 2), 256, 0, stream>>>(XTb, DTt, CUMS, SCH);
  state_combine_kernel<<<256, 256, 0, stream>>>(SCH, CUMS, SPREV);
  yscan_kernel<<<dim3(8, 128), 256, 0, stream>>>(XTb, DTt, CUMS, SH, SPREV, Yb16);
  combine_kernel<<<4096, 256, 0, stream>>>(Yb16, XTb, FCD, Dp, Zb, norm_w, YPb);
  cast_bf16_kernel<<<2048, 256, 0, stream>>>(out_proj_w, Wob);
  gemm_bf16<<<dim3(8, 32), 256, 0, stream>>>(YPb, 2048, Wob, 2048, out, 1024, 2048);
}

// Round 10
// 386.213 us; speedup vs baseline: 1.1544x; 1.1337x over previous
//
#include <hip/hip_runtime.h>
#include <hip/hip_bf16.h>
#include <math.h>

#define D_STATE   64
#define HEADDIM   64
#define D_INNER   2048
#define NHEADS    32
#define GN        64
#define CONV_DIM  2304
#define D_IN_PROJ 4416
#define ZLD       4352      /* z + xBC columns only (dt handled separately) */
#define K_SP      7
#define K_TP      4
#define CHUNK     256
#define BATCHN    2
#define FRAMES    8
#define SPATIAL   256
#define SEQLEN    2048
#define NCH       8
#define MTOT      4096

typedef __attribute__((ext_vector_type(8))) short short8;
typedef __attribute__((ext_vector_type(8))) unsigned short ushort8v;
typedef __attribute__((ext_vector_type(4))) float floatx4;

__device__ __forceinline__ float silu_f(float x) { return x / (1.f + __expf(-x)); }
__device__ __forceinline__ int flip_l(int l) { return (l & ~7) | (7 - (l & 7)); }
__device__ __forceinline__ unsigned short f2bf(float f) {
  unsigned int u = __float_as_uint(f);
  unsigned int r = (u + 0x7fffu + ((u >> 16) & 1u)) >> 16;
  return (unsigned short)r;
}
__device__ __forceinline__ float bf2f(unsigned short s) {
  return __uint_as_float(((unsigned int)s) << 16);
}
__device__ __forceinline__ void gload_lds16(const unsigned short* g, unsigned short* l) {
  __builtin_amdgcn_global_load_lds((const __attribute__((address_space(1))) void*)g,
                                   (__attribute__((address_space(3))) void*)l, 16, 0, 0);
}

// ---------------- f32 -> bf16 cast (two tensors, one launch) ----------------
__global__ __launch_bounds__(256) void cast2_bf16_kernel(const float* __restrict__ a,
                                                         unsigned short* __restrict__ oa,
                                                         int na_blocks,
                                                         const float* __restrict__ b,
                                                         unsigned short* __restrict__ ob) {
  int bid = blockIdx.x;
  const float* in;
  unsigned short* out;
  size_t i;
  if (bid < na_blocks) {
    in = a; out = oa;
    i = ((size_t)bid * 256 + threadIdx.x) * 4;
  } else {
    in = b; out = ob;
    i = ((size_t)(bid - na_blocks) * 256 + threadIdx.x) * 4;
  }
  float4 v = *(const float4*)(in + i);
  ushort4 o;
  o.x = f2bf(v.x); o.y = f2bf(v.y); o.z = f2bf(v.z); o.w = f2bf(v.w);
  *(ushort4*)(out + i) = o;
}

__global__ __launch_bounds__(256) void cast_bf16_kernel(const float* __restrict__ in,
                                                        unsigned short* __restrict__ out) {
  size_t i = ((size_t)blockIdx.x * 256 + threadIdx.x) * 4;
  float4 v = *(const float4*)(in + i);
  ushort4 o;
  o.x = f2bf(v.x); o.y = f2bf(v.y); o.z = f2bf(v.z); o.w = f2bf(v.w);
  *(ushort4*)(out + i) = o;
}

// ---------------- bf16 MFMA GEMM (f32 out): C = A * B^T ----------------
__global__ __launch_bounds__(256) void gemm_bf16(
    const unsigned short* __restrict__ A, int lda,
    const unsigned short* __restrict__ B, int ldb,
    float* __restrict__ C, int ldc, int K) {
  __shared__ unsigned short As[128 * 32];
  __shared__ unsigned short Bs[128 * 32];
  const int tid = threadIdx.x;
  const int lane = tid & 63;
  const int w = tid >> 6;
  const int m0 = blockIdx.y * 128;
  const int n0 = blockIdx.x * 128;
  const int wm = (w >> 1) * 64;
  const int wn = (w & 1) * 64;
  const int srow = lane >> 2;
  const int scol = (lane & 3) * 8;
  floatx4 acc[4][4] = {};
  for (int k0 = 0; k0 < K; k0 += 32) {
#pragma unroll
    for (int it = 0; it < 2; ++it) {
      int ch = it * 4 + w;
      gload_lds16(A + (size_t)(m0 + ch * 16 + srow) * lda + k0 + scol, &As[ch * 512]);
      gload_lds16(B + (size_t)(n0 + ch * 16 + srow) * ldb + k0 + scol, &Bs[ch * 512]);
    }
    __syncthreads();
    const int fr = lane & 15;
    const int kq = (lane >> 4) * 8;
    short8 af[4], bfr[4];
#pragma unroll
    for (int i = 0; i < 4; ++i)
      af[i] = *(const short8*)&As[(wm + i * 16 + fr) * 32 + kq];
#pragma unroll
    for (int j = 0; j < 4; ++j)
      bfr[j] = *(const short8*)&Bs[(wn + j * 16 + fr) * 32 + kq];
#pragma unroll
    for (int i = 0; i < 4; ++i)
#pragma unroll
      for (int j = 0; j < 4; ++j)
        acc[i][j] = __builtin_amdgcn_mfma_f32_16x16x32_bf16(af[i], bfr[j], acc[i][j], 0, 0, 0);
    __syncthreads();
  }
  const int col = lane & 15;
  const int rg = (lane >> 4) * 4;
#pragma unroll
  for (int i = 0; i < 4; ++i)
#pragma unroll
    for (int j = 0; j < 4; ++j)
#pragma unroll
      for (int r = 0; r < 4; ++r)
        C[(size_t)(m0 + wm + i * 16 + rg + r) * ldc + (n0 + wn + j * 16 + col)] = acc[i][j][r];
}

// ---------------- bf16 MFMA GEMM (bf16 out, vectorized epilogue) ----------------
__global__ __launch_bounds__(256) void gemm_bf16_bf16out(
    const unsigned short* __restrict__ A, int lda,
    const unsigned short* __restrict__ B, int ldb,
    unsigned short* __restrict__ C, int ldc, int K) {
  __shared__ unsigned short As[128 * 32];
  __shared__ unsigned short Bs[128 * 32];
  const int tid = threadIdx.x;
  const int lane = tid & 63;
  const int w = tid >> 6;
  const int m0 = blockIdx.y * 128;
  const int n0 = blockIdx.x * 128;
  const int wm = (w >> 1) * 64;
  const int wn = (w & 1) * 64;
  const int srow = lane >> 2;
  const int scol = (lane & 3) * 8;
  floatx4 acc[4][4] = {};
  for (int k0 = 0; k0 < K; k0 += 32) {
#pragma unroll
    for (int it = 0; it < 2; ++it) {
      int ch = it * 4 + w;
      gload_lds16(A + (size_t)(m0 + ch * 16 + srow) * lda + k0 + scol, &As[ch * 512]);
      gload_lds16(B + (size_t)(n0 + ch * 16 + srow) * ldb + k0 + scol, &Bs[ch * 512]);
    }
    __syncthreads();
    const int fr = lane & 15;
    const int kq = (lane >> 4) * 8;
    short8 af[4], bfr[4];
#pragma unroll
    for (int i = 0; i < 4; ++i)
      af[i] = *(const short8*)&As[(wm + i * 16 + fr) * 32 + kq];
#pragma unroll
    for (int j = 0; j < 4; ++j)
      bfr[j] = *(const short8*)&Bs[(wn + j * 16 + fr) * 32 + kq];
#pragma unroll
    for (int i = 0; i < 4; ++i)
#pragma unroll
      for (int j = 0; j < 4; ++j)
        acc[i][j] = __builtin_amdgcn_mfma_f32_16x16x32_bf16(af[i], bfr[j], acc[i][j], 0, 0, 0);
    __syncthreads();
  }
  // epilogue: per-wave LDS transpose (reuse As), ushort8 coalesced stores
  const int fr = lane & 15;
  const int rg = (lane >> 4) * 4;
  unsigned short* Ew = &As[w * 1024];
  const int rr = lane >> 3;
  const int c8 = (lane & 7) * 8;
#pragma unroll
  for (int i = 0; i < 4; ++i) {
#pragma unroll
    for (int q = 0; q < 4; ++q)
#pragma unroll
      for (int j = 0; j < 4; ++j)
        Ew[(rg + q) * 64 + j * 16 + fr] = f2bf(acc[i][j][q]);
    ushort8v v0 = *(const ushort8v*)&Ew[rr * 64 + c8];
    ushort8v v1 = *(const ushort8v*)&Ew[(rr + 8) * 64 + c8];
    *(ushort8v*)(C + (size_t)(m0 + wm + i * 16 + rr) * ldc + n0 + wn + c8) = v0;
    *(ushort8v*)(C + (size_t)(m0 + wm + i * 16 + rr + 8) * ldc + n0 + wn + c8) = v1;
  }
}

// ---------------- tall-skinny MFMA GEMM: C[M x N(16|32|64)] = A(bf16) @ B(f32)^T ----------------
// block = 16 m-rows, 4 waves split K; A-frags straight from global (k-contiguous),
// B (tiny, L2-resident) cast inline; 4-way cross-wave LDS reduction.
__global__ __launch_bounds__(256) void gemm_ts_mfma(
    const unsigned short* __restrict__ A, int lda,
    const float* __restrict__ B, int ldb,
    float* __restrict__ C, int ldc, int N, int K) {
  __shared__ float red[4][1024];
  const int tid = threadIdx.x;
  const int lane = tid & 63;
  const int w = tid >> 6;
  const int m0 = blockIdx.x * 16;
  const int fr = lane & 15;
  const int kq = (lane >> 4) * 8;
  const int nt = N >> 4;
  const int kseg = K >> 2;
  const int k0 = w * kseg;
  floatx4 acc[4] = {};
  for (int k = k0; k < k0 + kseg; k += 32) {
    short8 af = *(const short8*)(A + (size_t)(m0 + fr) * lda + k + kq);
    for (int j = 0; j < nt; ++j) {
      const float* bp = B + (size_t)(j * 16 + fr) * ldb + k + kq;
      float4 b0 = *(const float4*)bp;
      float4 b1 = *(const float4*)(bp + 4);
      short8 bf8;
      bf8[0] = (short)f2bf(b0.x); bf8[1] = (short)f2bf(b0.y);
      bf8[2] = (short)f2bf(b0.z); bf8[3] = (short)f2bf(b0.w);
      bf8[4] = (short)f2bf(b1.x); bf8[5] = (short)f2bf(b1.y);
      bf8[6] = (short)f2bf(b1.z); bf8[7] = (short)f2bf(b1.w);
      acc[j] = __builtin_amdgcn_mfma_f32_16x16x32_bf16(af, bf8, acc[j], 0, 0, 0);
    }
  }
  const int rg = (lane >> 4) * 4;
  for (int j = 0; j < nt; ++j)
#pragma unroll
    for (int q = 0; q < 4; ++q)
      red[w][j * 256 + (rg + q) * 16 + fr] = acc[j][q];
  __syncthreads();
  const int entries = nt * 256;
  for (int e = tid; e < entries; e += 256) {
    float s = red[0][e] + red[1][e] + red[2][e] + red[3][e];
    int j = e >> 8, idx = e & 255, row = idx >> 4, col = idx & 15;
    C[(size_t)(m0 + row) * ldc + j * 16 + col] = s;
  }
}

// ---------------- dt = softplus(dt_raw + bias), flip for reverse; + chunk-local cumsum ----------------
__global__ __launch_bounds__(256) void dtscan_kernel(const float* __restrict__ DTraw,
                                                     const float* __restrict__ dt_bias,
                                                     const float* __restrict__ A_log,
                                                     float* __restrict__ DTt,
                                                     float* __restrict__ CUMS) {
  __shared__ float sc[256];
  int tid = threadIdx.x;
  int idx = blockIdx.x * 256 + tid;
  int l  = idx & 2047;
  int rh = idx >> 11;
  int h  = rh & 31;
  int r  = rh >> 5;
  int bi = r & 1;
  int ls = (r < 2) ? l : flip_l(l);
  int ch = (r < 2) ? h : NHEADS + h;
  float raw = DTraw[((size_t)bi * SEQLEN + ls) * 64 + ch] + dt_bias[h];
  float dtv = (raw > 20.f) ? raw : log1pf(__expf(raw));
  DTt[idx] = dtv;
  float A = -__expf(A_log[h]);
  float run = dtv * A;
  sc[tid] = run;
  __syncthreads();
#pragma unroll
  for (int ofs = 1; ofs < 256; ofs <<= 1) {
    float add = (tid >= ofs) ? sc[tid - ofs] : 0.f;
    __syncthreads();
    run += add;
    sc[tid] = run;
    __syncthreads();
  }
  CUMS[idx] = run;
}

// ---------------- fused convs: bf16 in/out, register sliding-window ----------------
__global__ __launch_bounds__(256) void conv_fused2_kernel(const unsigned short* __restrict__ Zb,
                                                          const float* __restrict__ wsp,
                                                          const float* __restrict__ bsp,
                                                          const float* __restrict__ wtp,
                                                          const float* __restrict__ btp,
                                                          unsigned short* __restrict__ XTb) {
  __shared__ float4 xsl[8][8][32];
  const int tid = threadIdx.x;
  const int g  = tid & 31;
  const int fr = tid >> 5;
  const int c  = blockIdx.x * 128 + g * 4;
  const int s0 = blockIdx.y * 8;
  const int bi = blockIdx.z;
  float wsp_r[4][K_SP];
#pragma unroll
  for (int ch = 0; ch < 4; ++ch)
#pragma unroll
    for (int j = 0; j < K_SP; ++j) wsp_r[ch][j] = wsp[(c + ch) * K_SP + j];
  float4 bsp4 = *(const float4*)(bsp + c);
  float4 z[14];
#pragma unroll
  for (int i = 0; i < 14; ++i) {
    int ss = s0 - 3 + i;
    if (0 <= ss && ss < SPATIAL) {
      ushort4 v = *(const ushort4*)(Zb + ((size_t)bi * SEQLEN + (ss*8 + fr)) * ZLD + D_INNER + c);
      z[i] = make_float4(bf2f(v.x), bf2f(v.y), bf2f(v.z), bf2f(v.w));
    } else {
      z[i] = make_float4(0.f, 0.f, 0.f, 0.f);
    }
  }
#pragma unroll
  for (int so = 0; so < 8; ++so) {
    float4 a = bsp4;
#pragma unroll
    for (int j = 0; j < K_SP; ++j) {
      a.x += wsp_r[0][j] * z[so + j].x;
      a.y += wsp_r[1][j] * z[so + j].y;
      a.z += wsp_r[2][j] * z[so + j].z;
      a.w += wsp_r[3][j] * z[so + j].w;
    }
    a.x = silu_f(a.x); a.y = silu_f(a.y); a.z = silu_f(a.z); a.w = silu_f(a.w);
    xsl[fr][so][g] = a;
  }
  __syncthreads();
  float wtp_r[4][K_TP];
#pragma unroll
  for (int ch = 0; ch < 4; ++ch)
#pragma unroll
    for (int j = 0; j < K_TP; ++j) wtp_r[ch][j] = wtp[(c + ch) * K_TP + j];
  float4 btp4 = *(const float4*)(btp + c);
#pragma unroll
  for (int so = 0; so < 8; ++so) {
    float4 t = btp4;
#pragma unroll
    for (int j = 0; j < K_TP; ++j) {
      int ff = fr + j - (K_TP - 1);
      if (ff >= 0) {
        float4 xv = xsl[ff][so][g];
        t.x += wtp_r[0][j] * xv.x;
        t.y += wtp_r[1][j] * xv.y;
        t.z += wtp_r[2][j] * xv.z;
        t.w += wtp_r[3][j] * xv.w;
      }
    }
    ushort4 o;
    o.x = f2bf(silu_f(t.x)); o.y = f2bf(silu_f(t.y));
    o.z = f2bf(silu_f(t.z)); o.w = f2bf(silu_f(t.w));
    *(ushort4*)(XTb + ((size_t)bi * SEQLEN + ((s0 + so)*8 + fr)) * CONV_DIM + c) = o;
  }
}

// ---------------- CB[t][s] = sum_n C[t][n] B[s][n], per (r,c)  (t-major) ----------------
__global__ __launch_bounds__(256) void cb_kernel(const unsigned short* __restrict__ XTb,
                                                 float* __restrict__ CBs) {
  __shared__ float Ct[64][65];
  __shared__ float Bt[64][65];
  int tid = threadIdx.x;
  int t0 = (blockIdx.x & 3) * 64;
  int s0 = (blockIdx.x >> 2) * 64;
  if (s0 > t0) return;
  int c = blockIdx.y;
  int r = blockIdx.z;
  int bi = r & 1;
  int bOff = D_INNER + ((r < 2) ? 0 : 2*GN);
  int cOff = bOff + GN;
  int lrow = tid >> 4;
  int n4 = (tid & 15) << 2;
#pragma unroll
  for (int rep = 0; rep < 4; ++rep) {
    int tl = rep * 16 + lrow;
    int Lc = c * CHUNK + t0 + tl;
    int Ls = c * CHUNK + s0 + tl;
    if (r >= 2) { Lc = flip_l(Lc); Ls = flip_l(Ls); }
    ushort4 cv = *(const ushort4*)(XTb + ((size_t)bi*SEQLEN + Lc)*CONV_DIM + cOff + n4);
    ushort4 bv = *(const ushort4*)(XTb + ((size_t)bi*SEQLEN + Ls)*CONV_DIM + bOff + n4);
    Ct[n4+0][tl] = bf2f(cv.x); Ct[n4+1][tl] = bf2f(cv.y);
    Ct[n4+2][tl] = bf2f(cv.z); Ct[n4+3][tl] = bf2f(cv.w);
    Bt[n4+0][tl] = bf2f(bv.x); Bt[n4+1][tl] = bf2f(bv.y);
    Bt[n4+2][tl] = bf2f(bv.z); Bt[n4+3][tl] = bf2f(bv.w);
  }
  __syncthreads();
  int txx = tid & 15;
  int tyy = tid >> 4;
  float acc[4][4] = {{0.f,0.f,0.f,0.f},{0.f,0.f,0.f,0.f},{0.f,0.f,0.f,0.f},{0.f,0.f,0.f,0.f}};
#pragma unroll
  for (int n = 0; n < D_STATE; ++n) {
    float cr[4], br[4];
#pragma unroll
    for (int i = 0; i < 4; ++i) cr[i] = Ct[n][tyy + 16*i];
#pragma unroll
    for (int j = 0; j < 4; ++j) br[j] = Bt[n][txx + 16*j];
#pragma unroll
    for (int i = 0; i < 4; ++i)
#pragma unroll
      for (int j = 0; j < 4; ++j)
        acc[i][j] += cr[i] * br[j];
  }
  size_t base = (((size_t)r*NCH + c) * CHUNK) * CHUNK;
#pragma unroll
  for (int i = 0; i < 4; ++i)
#pragma unroll
    for (int j = 0; j < 4; ++j)
      CBs[base + (size_t)(t0 + tyy + 16*i)*CHUNK + (s0 + txx + 16*j)] = acc[i][j];
}

// ---------------- per-chunk state sums (MFMA, forward r=0,1 only) ----------------
__global__ __launch_bounds__(256) void chunk_state_kernel(const unsigned short* __restrict__ XTb,
                                                          const float* __restrict__ DTt,
                                                          const float* __restrict__ CUMS,
                                                          float* __restrict__ SCH) {
  __shared__ unsigned short Xb[64][40];
  __shared__ unsigned short Bb[64][40];
  int tid = threadIdx.x;
  int lane = tid & 63;
  int w = tid >> 6;
  int c = blockIdx.x;
  int h = blockIdx.y;
  int r = blockIdx.z;
  int bi = r;
  int rh = r * NHEADS + h;
  float cl = CUMS[(size_t)rh*SEQLEN + c*CHUNK + 255];
  const int fr = lane & 15;
  const int kq = (lane >> 4) * 8;
  floatx4 acc[4] = {};
  for (int sl = 0; sl < 8; ++sl) {
    int s0 = sl * 32;
    __syncthreads();
    {
      int srow = tid >> 3;
      int cg = (tid & 7) * 8;
      int l = c*CHUNK + s0 + srow;
      float g = __expf(cl - CUMS[(size_t)rh*SEQLEN + l]) * DTt[(size_t)rh*SEQLEN + l];
      const unsigned short* row = XTb + ((size_t)bi*SEQLEN + l)*CONV_DIM;
      ushort4 x0 = *(const ushort4*)(row + h*HEADDIM + cg);
      ushort4 x1 = *(const ushort4*)(row + h*HEADDIM + cg + 4);
      ushort4 b0 = *(const ushort4*)(row + D_INNER + cg);
      ushort4 b1 = *(const ushort4*)(row + D_INNER + cg + 4);
      Xb[cg+0][srow] = f2bf(g*bf2f(x0.x)); Xb[cg+1][srow] = f2bf(g*bf2f(x0.y));
      Xb[cg+2][srow] = f2bf(g*bf2f(x0.z)); Xb[cg+3][srow] = f2bf(g*bf2f(x0.w));
      Xb[cg+4][srow] = f2bf(g*bf2f(x1.x)); Xb[cg+5][srow] = f2bf(g*bf2f(x1.y));
      Xb[cg+6][srow] = f2bf(g*bf2f(x1.z)); Xb[cg+7][srow] = f2bf(g*bf2f(x1.w));
      Bb[cg+0][srow] = b0.x; Bb[cg+1][srow] = b0.y;
      Bb[cg+2][srow] = b0.z; Bb[cg+3][srow] = b0.w;
      Bb[cg+4][srow] = b1.x; Bb[cg+5][srow] = b1.y;
      Bb[cg+6][srow] = b1.z; Bb[cg+7][srow] = b1.w;
    }
    __syncthreads();
    short8 af = *(const short8*)&Xb[w*16 + fr][kq];
#pragma unroll
    for (int j = 0; j < 4; ++j) {
      short8 bf8 = *(const short8*)&Bb[j*16 + fr][kq];
      acc[j] = __builtin_amdgcn_mfma_f32_16x16x32_bf16(af, bf8, acc[j], 0, 0, 0);
    }
  }
  const int col = lane & 15;
  const int rg = (lane >> 4) * 4;
  size_t base = (((size_t)r*NCH + c)*NHEADS + h) * (size_t)(HEADDIM*D_STATE);
#pragma unroll
  for (int j = 0; j < 4; ++j)
#pragma unroll
    for (int q = 0; q < 4; ++q)
      SCH[base + (size_t)(w*16 + rg + q)*D_STATE + j*16 + col] = acc[j][q];
}

// ---------------- prefix-combine chunk states -> SPREV ----------------
__global__ __launch_bounds__(256) void state_combine_kernel(const float* __restrict__ SCH,
                                                            const float* __restrict__ CUMS,
                                                            float* __restrict__ SPREV) {
  int bid = blockIdx.x;
  int pq = bid & 3;
  int h = (bid >> 2) & 31;
  int r = bid >> 7;
  int tid = threadIdx.x;
  int p = pq*16 + (tid >> 4);
  int n = (tid & 15) * 4;
  float4 S = make_float4(0.f, 0.f, 0.f, 0.f);
  for (int c = 0; c < NCH; ++c) {
    size_t off = ((((size_t)r*NCH + c)*NHEADS + h)*HEADDIM + p)*D_STATE + n;
    *(float4*)(SPREV + off) = S;
    float dec = __expf(CUMS[((size_t)r*NHEADS + h)*SEQLEN + c*CHUNK + 255]);
    float4 v = *(const float4*)(SCH + off);
    S.x = dec*S.x + v.x; S.y = dec*S.y + v.y;
    S.z = dec*S.z + v.z; S.w = dec*S.w + v.w;
  }
}

// ---------------- Y = intra(triangular, MFMA) + inter (MFMA, fwd only), bf16 out ----------------
__global__ __launch_bounds__(256) void yscan_kernel(const unsigned short* __restrict__ XTb,
                                                    const float* __restrict__ DTt,
                                                    const float* __restrict__ CUMS,
                                                    const float* __restrict__ CBs,
                                                    const float* __restrict__ SPREV,
                                                    unsigned short* __restrict__ Yb16) {
  __shared__ unsigned short Xb[64][40];
  __shared__ float dts[CHUNK];
  __shared__ float cums[CHUNK];
  int tid = threadIdx.x;
  int lane = tid & 63;
  int w = tid >> 6;
  int c = blockIdx.x;
  int rh = blockIdx.y;
  int h = rh & 31;
  int r = rh >> 5;
  int bi = r & 1;
  dts[tid]  = DTt[(size_t)rh*SEQLEN + c*CHUNK + tid];
  cums[tid] = CUMS[(size_t)rh*SEQLEN + c*CHUNK + tid];
  __syncthreads();
  const int fr = lane & 15;
  const int kq = (lane >> 4) * 8;
  const int wt0 = w * 64;
  float ct[4];
#pragma unroll
  for (int i = 0; i < 4; ++i) ct[i] = cums[wt0 + i*16 + fr];
  floatx4 acc[4][4] = {};
  size_t cbbase = (((size_t)r*NCH + c) * CHUNK) * CHUNK;
  const int maxsl = 2*w + 1;
  for (int sl = 0; sl < 8; ++sl) {
    int s0 = sl * 32;
    __syncthreads();
    {
      int srow = tid >> 3;
      int p0 = (tid & 7) * 4;
      int L = c*CHUNK + s0 + srow;
      if (r >= 2) L = flip_l(L);
      const unsigned short* xrow = XTb + ((size_t)bi*SEQLEN + L)*CONV_DIM + h*HEADDIM;
#pragma unroll
      for (int half = 0; half < 2; ++half) {
        ushort4 v = *(const ushort4*)(xrow + p0 + half*32);
        Xb[p0 + half*32 + 0][srow] = v.x;
        Xb[p0 + half*32 + 1][srow] = v.y;
        Xb[p0 + half*32 + 2][srow] = v.z;
        Xb[p0 + half*32 + 3][srow] = v.w;
      }
    }
    __syncthreads();
    if (sl <= maxsl) {
      float cs[8], dtv[8];
#pragma unroll
      for (int j = 0; j < 8; ++j) { cs[j] = cums[s0 + kq + j]; dtv[j] = dts[s0 + kq + j]; }
      short8 bfr[4];
#pragma unroll
      for (int j = 0; j < 4; ++j)
        bfr[j] = *(const short8*)&Xb[j*16 + fr][kq];
#pragma unroll
      for (int i = 0; i < 4; ++i) {
        int t = wt0 + i*16 + fr;
        const float* cbrow = CBs + cbbase + (size_t)t*CHUNK + s0 + kq;
        float4 c0 = *(const float4*)cbrow;
        float4 c1 = *(const float4*)(cbrow + 4);
        float cb[8] = {c0.x,c0.y,c0.z,c0.w,c1.x,c1.y,c1.z,c1.w};
        short8 af;
#pragma unroll
        for (int j = 0; j < 8; ++j) {
          int s = s0 + kq + j;
          float wv = (s <= t) ? cb[j] * __expf(ct[i] - cs[j]) * dtv[j] : 0.f;
          af[j] = (short)f2bf(wv);
        }
#pragma unroll
        for (int j = 0; j < 4; ++j)
          acc[i][j] = __builtin_amdgcn_mfma_f32_16x16x32_bf16(af, bfr[j], acc[i][j], 0, 0, 0);
      }
    }
  }
  if (r < 2) {
    float ect[4];
#pragma unroll
    for (int i = 0; i < 4; ++i) ect[i] = __expf(ct[i]);
    const float* spbase = SPREV + (((size_t)r*NCH + c)*NHEADS + h) * (size_t)(HEADDIM*D_STATE);
#pragma unroll
    for (int ns = 0; ns < 2; ++ns) {
      int n0 = ns * 32;
      short8 bfr[4];
#pragma unroll
      for (int j = 0; j < 4; ++j) {
        const float* sp = spbase + (size_t)(j*16 + fr)*D_STATE + n0 + kq;
        float4 s0v = *(const float4*)sp;
        float4 s1v = *(const float4*)(sp + 4);
        short8 bb;
        bb[0]=(short)f2bf(s0v.x); bb[1]=(short)f2bf(s0v.y); bb[2]=(short)f2bf(s0v.z); bb[3]=(short)f2bf(s0v.w);
        bb[4]=(short)f2bf(s1v.x); bb[5]=(short)f2bf(s1v.y); bb[6]=(short)f2bf(s1v.z); bb[7]=(short)f2bf(s1v.w);
        bfr[j] = bb;
      }
#pragma unroll
      for (int i = 0; i < 4; ++i) {
        int t = wt0 + i*16 + fr;
        const unsigned short* crow = XTb + ((size_t)bi*SEQLEN + c*CHUNK + t)*CONV_DIM + D_INNER + GN + n0 + kq;
        ushort4 c0 = *(const ushort4*)crow;
        ushort4 c1 = *(const ushort4*)(crow + 4);
        short8 af;
        af[0]=(short)f2bf(bf2f(c0.x)*ect[i]); af[1]=(short)f2bf(bf2f(c0.y)*ect[i]);
        af[2]=(short)f2bf(bf2f(c0.z)*ect[i]); af[3]=(short)f2bf(bf2f(c0.w)*ect[i]);
        af[4]=(short)f2bf(bf2f(c1.x)*ect[i]); af[5]=(short)f2bf(bf2f(c1.y)*ect[i]);
        af[6]=(short)f2bf(bf2f(c1.z)*ect[i]); af[7]=(short)f2bf(bf2f(c1.w)*ect[i]);
#pragma unroll
        for (int j = 0; j < 4; ++j)
          acc[i][j] = __builtin_amdgcn_mfma_f32_16x16x32_bf16(af, bfr[j], acc[i][j], 0, 0, 0);
      }
    }
  }
  // bf16 epilogue: per-wave LDS transpose (reuse Xb; barrier — wave 0 races ahead)
  __syncthreads();
  unsigned short* Ew = (unsigned short*)Xb + w * 1024;
  const int rg = (lane >> 4) * 4;
  const int rr = lane >> 3;
  const int c8 = (lane & 7) * 8;
  size_t ybase = ((size_t)r*SEQLEN + c*CHUNK)*D_INNER + h*HEADDIM;
#pragma unroll
  for (int i = 0; i < 4; ++i) {
#pragma unroll
    for (int q = 0; q < 4; ++q)
#pragma unroll
      for (int j = 0; j < 4; ++j)
        Ew[(rg + q) * 64 + j * 16 + fr] = f2bf(acc[i][j][q]);
    ushort8v v0 = *(const ushort8v*)&Ew[rr * 64 + c8];
    ushort8v v1 = *(const ushort8v*)&Ew[(rr + 8) * 64 + c8];
    *(ushort8v*)(Yb16 + ybase + (size_t)(wt0 + i*16 + rr) * D_INNER + c8) = v0;
    *(ushort8v*)(Yb16 + ybase + (size_t)(wt0 + i*16 + rr + 8) * D_INNER + c8) = v1;
  }
}

// ---------------- shifts + x_res + RMSNorm + gate (vectorized, -> bf16) ----------------
__global__ __launch_bounds__(256) void combine_kernel(const unsigned short* __restrict__ Y,
                                                      const unsigned short* __restrict__ XTb,
                                                      const float* __restrict__ FCD,
                                                      const float* __restrict__ Dp,
                                                      const unsigned short* __restrict__ Zb,
                                                      const float* __restrict__ norm_w,
                                                      unsigned short* __restrict__ YPb) {
  __shared__ float red[256];
  int row = blockIdx.x;
  int bi = row >> 11;
  int l = row & 2047;
  int s = l >> 3, fr = l & 7;
  int tid = threadIdx.x;
  int d0 = tid * 8;
  const unsigned short* yf = (l >= 1) ? Y + ((size_t)bi*SEQLEN + (l-1))*D_INNER + d0 : nullptr;
  const unsigned short* yr = (s >= 1) ? Y + ((size_t)(2+bi)*SEQLEN + ((s-1)*8 + (7-fr)))*D_INNER + d0 : nullptr;
  const unsigned short* xr = XTb + ((size_t)row)*CONV_DIM + d0;
  float fcv = FCD[(size_t)row*NHEADS + (d0 >> 6)] + Dp[d0 >> 6];
  ushort8v xv8 = *(const ushort8v*)xr;
  float v[8];
#pragma unroll
  for (int q = 0; q < 8; ++q) v[q] = bf2f(xv8[q]) * fcv;
  if (yf) {
    ushort8v a = *(const ushort8v*)yf;
#pragma unroll
    for (int q = 0; q < 8; ++q) v[q] += bf2f(a[q]);
  }
  if (yr) {
    ushort8v a = *(const ushort8v*)yr;
#pragma unroll
    for (int q = 0; q < 8; ++q) v[q] += bf2f(a[q]);
  }
  float ss = 0.f;
#pragma unroll
  for (int q = 0; q < 8; ++q) ss += v[q] * v[q];
  red[tid] = ss;
  __syncthreads();
  for (int ofs = 128; ofs > 0; ofs >>= 1) {
    if (tid < ofs) red[tid] += red[tid + ofs];
    __syncthreads();
  }
  float rs = rsqrtf(red[0] / (float)D_INNER + 1e-5f);
  ushort8v zv8 = *(const ushort8v*)(Zb + ((size_t)row)*ZLD + d0);
  float4 nw0 = *(const float4*)(norm_w + d0);
  float4 nw1 = *(const float4*)(norm_w + d0 + 4);
  float nw[8] = {nw0.x,nw0.y,nw0.z,nw0.w,nw1.x,nw1.y,nw1.z,nw1.w};
  ushort8v o;
#pragma unroll
  for (int q = 0; q < 8; ++q)
    o[q] = f2bf(v[q] * rs * nw[q] * silu_f(bf2f(zv8[q])));
  *(ushort8v*)(YPb + (size_t)row*D_INNER + d0) = o;
}

extern "C" void kernel_launch(void* const* d_in, const int* in_sizes, int n_in,
                              void* d_out, int out_size, void* d_ws, size_t ws_size,
                              hipStream_t stream) {
  (void)in_sizes; (void)n_in; (void)out_size; (void)ws_size;
  const float* u          = (const float*)d_in[0];
  const float* in_proj_w  = (const float*)d_in[1];
  const float* conv_sp_w  = (const float*)d_in[2];
  const float* conv_sp_b  = (const float*)d_in[3];
  const float* conv_tp_w  = (const float*)d_in[4];
  const float* conv_tp_b  = (const float*)d_in[5];
  const float* dt_bias    = (const float*)d_in[6];
  const float* A_log      = (const float*)d_in[7];
  const float* Dp         = (const float*)d_in[8];
  const float* fc_D_w     = (const float*)d_in[9];
  const float* norm_w     = (const float*)d_in[10];
  const float* out_proj_w = (const float*)d_in[11];
  float* out = (float*)d_out;
  float* ws = (float*)d_ws;

  // workspace layout (f32-element offsets; Z/XT/Y regions hold bf16)
  float* Z     = ws;                       // 17,825,792 slots (bf16 uses half)
  float* SH    = Z     + 17825792ULL;      // 9,437,184  (CBs -> YPb)
  float* XT    = SH    + 9437184ULL;       // 9,437,184  (bf16 uses half)
  float* DTt   = XT    + 9437184ULL;       // 262,144
  float* Yb    = DTt   + 262144ULL;        // 16,777,216 (bf16 Y uses half; staging + SCH early)
  float* SPREV = Yb    + 16777216ULL;      // 2,097,152
  float* FCD   = SPREV + 2097152ULL;       // 131,072
  float* DTraw = FCD   + 131072ULL;        // 262,144
  float* CUMS  = DTraw + 262144ULL;        // 262,144

  unsigned short* Zb   = (unsigned short*)Z;
  unsigned short* XTb  = (unsigned short*)XT;
  unsigned short* Yb16 = (unsigned short*)Yb;            // 16,777,216 shorts (first 8,388,608 floats)
  unsigned short* Ub   = (unsigned short*)Yb;            // staging (dead before yscan)
  unsigned short* Wb   = (unsigned short*)Yb + 4194304ULL;
  float* SCH = Yb + 8388608ULL;            // 2,097,152 floats (disjoint from Yb16)
  unsigned short* Wob = (unsigned short*)SPREV;          // 2,097,152 shorts (SPREV dead after yscan)
  unsigned short* YPb = (unsigned short*)SH;

  cast2_bf16_kernel<<<8448, 256, 0, stream>>>(u, Ub, 4096, in_proj_w, Wb);
  gemm_bf16_bf16out<<<dim3(34, 32), 256, 0, stream>>>(Ub, 1024, Wb, 1024, Zb, ZLD, 1024);
  // dt_raw = u @ W_dt^T  (tall-skinny MFMA, bf16 A; exp-path error ~6e-4, see R10 notes)
  gemm_ts_mfma<<<256, 256, 0, stream>>>(Ub, 1024, in_proj_w + 4352ULL*1024, 1024,
                                        DTraw, 64, 64, 1024);
  dtscan_kernel<<<1024, 256, 0, stream>>>(DTraw, dt_bias, A_log, DTt, CUMS);
  conv_fused2_kernel<<<dim3(18, 32, 2), 256, 0, stream>>>(Zb, conv_sp_w, conv_sp_b,
                                                          conv_tp_w, conv_tp_b, XTb);
  // FCD = x @ fc_D_w^T  (tall-skinny MFMA; x = first 2048 cols of XTb rows)
  gemm_ts_mfma<<<256, 256, 0, stream>>>(XTb, CONV_DIM, fc_D_w, 2048,
                                        FCD, 32, 32, 2048);
  cb_kernel<<<dim3(16, 8, 4), 256, 0, stream>>>(XTb, SH);
  chunk_state_kernel<<<dim3(NCH, NHEADS, 2), 256, 0, stream>>>(XTb, DTt, CUMS, SCH);
  state_combine_kernel<<<256, 256, 0, stream>>>(SCH, CUMS, SPREV);
  yscan_kernel<<<dim3(8, 128), 256, 0, stream>>>(XTb, DTt, CUMS, SH, SPREV, Yb16);
  combine_kernel<<<4096, 256, 0, stream>>>(Yb16, XTb, FCD, Dp, Zb, norm_w, YPb);
  cast_bf16_kernel<<<2048, 256, 0, stream>>>(out_proj_w, Wob);
  gemm_bf16<<<dim3(8, 32), 256, 0, stream>>>(YPb, 2048, Wob, 2048, out, 1024, 2048);
}

// Round 11
// 364.574 us; speedup vs baseline: 1.2229x; 1.0594x over previous
//
#include <hip/hip_runtime.h>
#include <hip/hip_bf16.h>
#include <math.h>

#define D_STATE   64
#define HEADDIM   64
#define D_INNER   2048
#define NHEADS    32
#define GN        64
#define CONV_DIM  2304
#define D_IN_PROJ 4416
#define ZLD       4352      /* z + xBC columns only (dt handled separately) */
#define K_SP      7
#define K_TP      4
#define CHUNK     256
#define BATCHN    2
#define FRAMES    8
#define SPATIAL   256
#define SEQLEN    2048
#define NCH       8
#define MTOT      4096

typedef __attribute__((ext_vector_type(8))) short short8;
typedef __attribute__((ext_vector_type(8))) unsigned short ushort8v;
typedef __attribute__((ext_vector_type(4))) float floatx4;

__device__ __forceinline__ float silu_f(float x) { return x / (1.f + __expf(-x)); }
__device__ __forceinline__ int flip_l(int l) { return (l & ~7) | (7 - (l & 7)); }
__device__ __forceinline__ unsigned short f2bf(float f) {
  unsigned int u = __float_as_uint(f);
  unsigned int r = (u + 0x7fffu + ((u >> 16) & 1u)) >> 16;
  return (unsigned short)r;
}
__device__ __forceinline__ float bf2f(unsigned short s) {
  return __uint_as_float(((unsigned int)s) << 16);
}
__device__ __forceinline__ void gload_lds16(const unsigned short* g, unsigned short* l) {
  __builtin_amdgcn_global_load_lds((const __attribute__((address_space(1))) void*)g,
                                   (__attribute__((address_space(3))) void*)l, 16, 0, 0);
}

// ---------------- f32 -> bf16 cast (three tensors, one launch) ----------------
__global__ __launch_bounds__(256) void cast3_bf16_kernel(const float* __restrict__ a,
                                                         unsigned short* __restrict__ oa,
                                                         int na,
                                                         const float* __restrict__ b,
                                                         unsigned short* __restrict__ ob,
                                                         int nb,
                                                         const float* __restrict__ c,
                                                         unsigned short* __restrict__ oc) {
  int bid = blockIdx.x;
  const float* in;
  unsigned short* out;
  size_t blk;
  if (bid < na)            { in = a; out = oa; blk = bid; }
  else if (bid < na + nb)  { in = b; out = ob; blk = bid - na; }
  else                     { in = c; out = oc; blk = bid - na - nb; }
  size_t i = (blk * 256 + threadIdx.x) * 4;
  float4 v = *(const float4*)(in + i);
  ushort4 o;
  o.x = f2bf(v.x); o.y = f2bf(v.y); o.z = f2bf(v.z); o.w = f2bf(v.w);
  *(ushort4*)(out + i) = o;
}

// ---- BK=64, XOR-swizzled LDS, 128x128 tile, bf16 out (in_proj) ----
// LDS layout: 16B unit (row, u) lives at slot row*8 + (u ^ (row&7)); the XOR is
// applied in the GLOBAL address so global_load_lds stays contiguous (m104).
__global__ __launch_bounds__(256) void gemm_bk64_bf16out(
    const unsigned short* __restrict__ A, int lda,
    const unsigned short* __restrict__ B, int ldb,
    unsigned short* __restrict__ C, int ldc, int K) {
  __shared__ unsigned short As[128 * 64];
  __shared__ unsigned short Bs[128 * 64];
  const int tid = threadIdx.x;
  const int lane = tid & 63;
  const int w = tid >> 6;
  const int m0 = blockIdx.y * 128;
  const int n0 = blockIdx.x * 128;
  const int wm = (w >> 1) * 64;
  const int wn = (w & 1) * 64;
  const int lrow = lane >> 3;            // 0..7 within 8-row group
  const int lperm = lane & 7;            // LDS slot within row
  floatx4 acc[4][4] = {};
  for (int k0 = 0; k0 < K; k0 += 64) {
#pragma unroll
    for (int j = 0; j < 8; ++j) {
      int g = j * 4 + w;                 // 0..31: 16 A-groups then 16 B-groups
      if (g < 16) {
        int row = g * 8 + lrow;
        int cg = (lperm ^ (row & 7)) * 8;
        gload_lds16(A + (size_t)(m0 + row) * lda + k0 + cg, &As[g * 512]);
      } else {
        int gb = g - 16;
        int row = gb * 8 + lrow;
        int cg = (lperm ^ (row & 7)) * 8;
        gload_lds16(B + (size_t)(n0 + row) * ldb + k0 + cg, &Bs[gb * 512]);
      }
    }
    __syncthreads();
    const int fr = lane & 15;
    const int kq = (lane >> 4) * 8;
#pragma unroll
    for (int kk = 0; kk < 64; kk += 32) {
      int u = (kk + kq) >> 3;
      short8 af[4], bfr[4];
#pragma unroll
      for (int i = 0; i < 4; ++i) {
        int row = wm + i * 16 + fr;
        af[i] = *(const short8*)&As[(row * 8 + (u ^ (row & 7))) * 8];
      }
#pragma unroll
      for (int j = 0; j < 4; ++j) {
        int row = wn + j * 16 + fr;
        bfr[j] = *(const short8*)&Bs[(row * 8 + (u ^ (row & 7))) * 8];
      }
#pragma unroll
      for (int i = 0; i < 4; ++i)
#pragma unroll
        for (int j = 0; j < 4; ++j)
          acc[i][j] = __builtin_amdgcn_mfma_f32_16x16x32_bf16(af[i], bfr[j], acc[i][j], 0, 0, 0);
    }
    __syncthreads();
  }
  // epilogue: per-wave LDS transpose (reuse As), ushort8 coalesced stores
  const int fr = lane & 15;
  const int rg = (lane >> 4) * 4;
  unsigned short* Ew = &As[w * 1024];
  const int rr = lane >> 3;
  const int c8 = (lane & 7) * 8;
#pragma unroll
  for (int i = 0; i < 4; ++i) {
#pragma unroll
    for (int q = 0; q < 4; ++q)
#pragma unroll
      for (int j = 0; j < 4; ++j)
        Ew[(rg + q) * 64 + j * 16 + fr] = f2bf(acc[i][j][q]);
    ushort8v v0 = *(const ushort8v*)&Ew[rr * 64 + c8];
    ushort8v v1 = *(const ushort8v*)&Ew[(rr + 8) * 64 + c8];
    *(ushort8v*)(C + (size_t)(m0 + wm + i * 16 + rr) * ldc + n0 + wn + c8) = v0;
    *(ushort8v*)(C + (size_t)(m0 + wm + i * 16 + rr + 8) * ldc + n0 + wn + c8) = v1;
  }
}

// ---- BK=64, XOR-swizzled, 64(m)x128(n) tile, f32 out (out_proj: 512 blocks) ----
__global__ __launch_bounds__(256) void gemm_m64_f32(
    const unsigned short* __restrict__ A, int lda,
    const unsigned short* __restrict__ B, int ldb,
    float* __restrict__ C, int ldc, int K) {
  __shared__ unsigned short As[64 * 64];
  __shared__ unsigned short Bs[128 * 64];
  const int tid = threadIdx.x;
  const int lane = tid & 63;
  const int w = tid >> 6;
  const int m0 = blockIdx.y * 64;
  const int n0 = blockIdx.x * 128;
  const int wm = (w >> 1) * 32;
  const int wn = (w & 1) * 64;
  const int lrow = lane >> 3;
  const int lperm = lane & 7;
  floatx4 acc[2][4] = {};
  for (int k0 = 0; k0 < K; k0 += 64) {
#pragma unroll
    for (int j = 0; j < 6; ++j) {
      int g = j * 4 + w;                 // 0..23: 8 A-groups then 16 B-groups
      if (g < 8) {
        int row = g * 8 + lrow;
        int cg = (lperm ^ (row & 7)) * 8;
        gload_lds16(A + (size_t)(m0 + row) * lda + k0 + cg, &As[g * 512]);
      } else {
        int gb = g - 8;
        int row = gb * 8 + lrow;
        int cg = (lperm ^ (row & 7)) * 8;
        gload_lds16(B + (size_t)(n0 + row) * ldb + k0 + cg, &Bs[gb * 512]);
      }
    }
    __syncthreads();
    const int fr = lane & 15;
    const int kq = (lane >> 4) * 8;
#pragma unroll
    for (int kk = 0; kk < 64; kk += 32) {
      int u = (kk + kq) >> 3;
      short8 af[2], bfr[4];
#pragma unroll
      for (int i = 0; i < 2; ++i) {
        int row = wm + i * 16 + fr;
        af[i] = *(const short8*)&As[(row * 8 + (u ^ (row & 7))) * 8];
      }
#pragma unroll
      for (int j = 0; j < 4; ++j) {
        int row = wn + j * 16 + fr;
        bfr[j] = *(const short8*)&Bs[(row * 8 + (u ^ (row & 7))) * 8];
      }
#pragma unroll
      for (int i = 0; i < 2; ++i)
#pragma unroll
        for (int j = 0; j < 4; ++j)
          acc[i][j] = __builtin_amdgcn_mfma_f32_16x16x32_bf16(af[i], bfr[j], acc[i][j], 0, 0, 0);
    }
    __syncthreads();
  }
  const int col = lane & 15;
  const int rg = (lane >> 4) * 4;
#pragma unroll
  for (int i = 0; i < 2; ++i)
#pragma unroll
    for (int j = 0; j < 4; ++j)
#pragma unroll
      for (int r = 0; r < 4; ++r)
        C[(size_t)(m0 + wm + i * 16 + rg + r) * ldc + (n0 + wn + j * 16 + col)] = acc[i][j][r];
}

// ---------------- tall-skinny MFMA GEMM: C[M x N(16|32|64)] = A(bf16) @ B(f32)^T ----------------
__global__ __launch_bounds__(256) void gemm_ts_mfma(
    const unsigned short* __restrict__ A, int lda,
    const float* __restrict__ B, int ldb,
    float* __restrict__ C, int ldc, int N, int K) {
  __shared__ float red[4][1024];
  const int tid = threadIdx.x;
  const int lane = tid & 63;
  const int w = tid >> 6;
  const int m0 = blockIdx.x * 16;
  const int fr = lane & 15;
  const int kq = (lane >> 4) * 8;
  const int nt = N >> 4;
  const int kseg = K >> 2;
  const int k0 = w * kseg;
  floatx4 acc[4] = {};
  for (int k = k0; k < k0 + kseg; k += 32) {
    short8 af = *(const short8*)(A + (size_t)(m0 + fr) * lda + k + kq);
    for (int j = 0; j < nt; ++j) {
      const float* bp = B + (size_t)(j * 16 + fr) * ldb + k + kq;
      float4 b0 = *(const float4*)bp;
      float4 b1 = *(const float4*)(bp + 4);
      short8 bf8;
      bf8[0] = (short)f2bf(b0.x); bf8[1] = (short)f2bf(b0.y);
      bf8[2] = (short)f2bf(b0.z); bf8[3] = (short)f2bf(b0.w);
      bf8[4] = (short)f2bf(b1.x); bf8[5] = (short)f2bf(b1.y);
      bf8[6] = (short)f2bf(b1.z); bf8[7] = (short)f2bf(b1.w);
      acc[j] = __builtin_amdgcn_mfma_f32_16x16x32_bf16(af, bf8, acc[j], 0, 0, 0);
    }
  }
  const int rg = (lane >> 4) * 4;
  for (int j = 0; j < nt; ++j)
#pragma unroll
    for (int q = 0; q < 4; ++q)
      red[w][j * 256 + (rg + q) * 16 + fr] = acc[j][q];
  __syncthreads();
  const int entries = nt * 256;
  for (int e = tid; e < entries; e += 256) {
    float s = red[0][e] + red[1][e] + red[2][e] + red[3][e];
    int j = e >> 8, idx = e & 255, row = idx >> 4, col = idx & 15;
    C[(size_t)(m0 + row) * ldc + j * 16 + col] = s;
  }
}

// ---------------- dt = softplus(dt_raw + bias), flip for reverse; + chunk-local cumsum ----------------
__global__ __launch_bounds__(256) void dtscan_kernel(const float* __restrict__ DTraw,
                                                     const float* __restrict__ dt_bias,
                                                     const float* __restrict__ A_log,
                                                     float* __restrict__ DTt,
                                                     float* __restrict__ CUMS) {
  __shared__ float sc[256];
  int tid = threadIdx.x;
  int idx = blockIdx.x * 256 + tid;
  int l  = idx & 2047;
  int rh = idx >> 11;
  int h  = rh & 31;
  int r  = rh >> 5;
  int bi = r & 1;
  int ls = (r < 2) ? l : flip_l(l);
  int ch = (r < 2) ? h : NHEADS + h;
  float raw = DTraw[((size_t)bi * SEQLEN + ls) * 64 + ch] + dt_bias[h];
  float dtv = (raw > 20.f) ? raw : log1pf(__expf(raw));
  DTt[idx] = dtv;
  float A = -__expf(A_log[h]);
  float run = dtv * A;
  sc[tid] = run;
  __syncthreads();
#pragma unroll
  for (int ofs = 1; ofs < 256; ofs <<= 1) {
    float add = (tid >= ofs) ? sc[tid - ofs] : 0.f;
    __syncthreads();
    run += add;
    sc[tid] = run;
    __syncthreads();
  }
  CUMS[idx] = run;
}

// ---------------- fused convs: bf16 in/out, register sliding-window ----------------
__global__ __launch_bounds__(256) void conv_fused2_kernel(const unsigned short* __restrict__ Zb,
                                                          const float* __restrict__ wsp,
                                                          const float* __restrict__ bsp,
                                                          const float* __restrict__ wtp,
                                                          const float* __restrict__ btp,
                                                          unsigned short* __restrict__ XTb) {
  __shared__ float4 xsl[8][8][32];
  const int tid = threadIdx.x;
  const int g  = tid & 31;
  const int fr = tid >> 5;
  const int c  = blockIdx.x * 128 + g * 4;
  const int s0 = blockIdx.y * 8;
  const int bi = blockIdx.z;
  float wsp_r[4][K_SP];
#pragma unroll
  for (int ch = 0; ch < 4; ++ch)
#pragma unroll
    for (int j = 0; j < K_SP; ++j) wsp_r[ch][j] = wsp[(c + ch) * K_SP + j];
  float4 bsp4 = *(const float4*)(bsp + c);
  float4 z[14];
#pragma unroll
  for (int i = 0; i < 14; ++i) {
    int ss = s0 - 3 + i;
    if (0 <= ss && ss < SPATIAL) {
      ushort4 v = *(const ushort4*)(Zb + ((size_t)bi * SEQLEN + (ss*8 + fr)) * ZLD + D_INNER + c);
      z[i] = make_float4(bf2f(v.x), bf2f(v.y), bf2f(v.z), bf2f(v.w));
    } else {
      z[i] = make_float4(0.f, 0.f, 0.f, 0.f);
    }
  }
#pragma unroll
  for (int so = 0; so < 8; ++so) {
    float4 a = bsp4;
#pragma unroll
    for (int j = 0; j < K_SP; ++j) {
      a.x += wsp_r[0][j] * z[so + j].x;
      a.y += wsp_r[1][j] * z[so + j].y;
      a.z += wsp_r[2][j] * z[so + j].z;
      a.w += wsp_r[3][j] * z[so + j].w;
    }
    a.x = silu_f(a.x); a.y = silu_f(a.y); a.z = silu_f(a.z); a.w = silu_f(a.w);
    xsl[fr][so][g] = a;
  }
  __syncthreads();
  float wtp_r[4][K_TP];
#pragma unroll
  for (int ch = 0; ch < 4; ++ch)
#pragma unroll
    for (int j = 0; j < K_TP; ++j) wtp_r[ch][j] = wtp[(c + ch) * K_TP + j];
  float4 btp4 = *(const float4*)(btp + c);
#pragma unroll
  for (int so = 0; so < 8; ++so) {
    float4 t = btp4;
#pragma unroll
    for (int j = 0; j < K_TP; ++j) {
      int ff = fr + j - (K_TP - 1);
      if (ff >= 0) {
        float4 xv = xsl[ff][so][g];
        t.x += wtp_r[0][j] * xv.x;
        t.y += wtp_r[1][j] * xv.y;
        t.z += wtp_r[2][j] * xv.z;
        t.w += wtp_r[3][j] * xv.w;
      }
    }
    ushort4 o;
    o.x = f2bf(silu_f(t.x)); o.y = f2bf(silu_f(t.y));
    o.z = f2bf(silu_f(t.z)); o.w = f2bf(silu_f(t.w));
    *(ushort4*)(XTb + ((size_t)bi * SEQLEN + ((s0 + so)*8 + fr)) * CONV_DIM + c) = o;
  }
}

// ---------------- CB[t][s] = sum_n C[t][n] B[s][n], per (r,c)  (t-major) ----------------
__global__ __launch_bounds__(256) void cb_kernel(const unsigned short* __restrict__ XTb,
                                                 float* __restrict__ CBs) {
  __shared__ float Ct[64][65];
  __shared__ float Bt[64][65];
  int tid = threadIdx.x;
  int t0 = (blockIdx.x & 3) * 64;
  int s0 = (blockIdx.x >> 2) * 64;
  if (s0 > t0) return;
  int c = blockIdx.y;
  int r = blockIdx.z;
  int bi = r & 1;
  int bOff = D_INNER + ((r < 2) ? 0 : 2*GN);
  int cOff = bOff + GN;
  int lrow = tid >> 4;
  int n4 = (tid & 15) << 2;
#pragma unroll
  for (int rep = 0; rep < 4; ++rep) {
    int tl = rep * 16 + lrow;
    int Lc = c * CHUNK + t0 + tl;
    int Ls = c * CHUNK + s0 + tl;
    if (r >= 2) { Lc = flip_l(Lc); Ls = flip_l(Ls); }
    ushort4 cv = *(const ushort4*)(XTb + ((size_t)bi*SEQLEN + Lc)*CONV_DIM + cOff + n4);
    ushort4 bv = *(const ushort4*)(XTb + ((size_t)bi*SEQLEN + Ls)*CONV_DIM + bOff + n4);
    Ct[n4+0][tl] = bf2f(cv.x); Ct[n4+1][tl] = bf2f(cv.y);
    Ct[n4+2][tl] = bf2f(cv.z); Ct[n4+3][tl] = bf2f(cv.w);
    Bt[n4+0][tl] = bf2f(bv.x); Bt[n4+1][tl] = bf2f(bv.y);
    Bt[n4+2][tl] = bf2f(bv.z); Bt[n4+3][tl] = bf2f(bv.w);
  }
  __syncthreads();
  int txx = tid & 15;
  int tyy = tid >> 4;
  float acc[4][4] = {{0.f,0.f,0.f,0.f},{0.f,0.f,0.f,0.f},{0.f,0.f,0.f,0.f},{0.f,0.f,0.f,0.f}};
#pragma unroll
  for (int n = 0; n < D_STATE; ++n) {
    float cr[4], br[4];
#pragma unroll
    for (int i = 0; i < 4; ++i) cr[i] = Ct[n][tyy + 16*i];
#pragma unroll
    for (int j = 0; j < 4; ++j) br[j] = Bt[n][txx + 16*j];
#pragma unroll
    for (int i = 0; i < 4; ++i)
#pragma unroll
      for (int j = 0; j < 4; ++j)
        acc[i][j] += cr[i] * br[j];
  }
  size_t base = (((size_t)r*NCH + c) * CHUNK) * CHUNK;
#pragma unroll
  for (int i = 0; i < 4; ++i)
#pragma unroll
    for (int j = 0; j < 4; ++j)
      CBs[base + (size_t)(t0 + tyy + 16*i)*CHUNK + (s0 + txx + 16*j)] = acc[i][j];
}

// ---------------- per-chunk state sums (MFMA, forward r=0,1 only) ----------------
__global__ __launch_bounds__(256) void chunk_state_kernel(const unsigned short* __restrict__ XTb,
                                                          const float* __restrict__ DTt,
                                                          const float* __restrict__ CUMS,
                                                          float* __restrict__ SCH) {
  __shared__ unsigned short Xb[64][40];
  __shared__ unsigned short Bb[64][40];
  int tid = threadIdx.x;
  int lane = tid & 63;
  int w = tid >> 6;
  int c = blockIdx.x;
  int h = blockIdx.y;
  int r = blockIdx.z;
  int bi = r;
  int rh = r * NHEADS + h;
  float cl = CUMS[(size_t)rh*SEQLEN + c*CHUNK + 255];
  const int fr = lane & 15;
  const int kq = (lane >> 4) * 8;
  floatx4 acc[4] = {};
  for (int sl = 0; sl < 8; ++sl) {
    int s0 = sl * 32;
    __syncthreads();
    {
      int srow = tid >> 3;
      int cg = (tid & 7) * 8;
      int l = c*CHUNK + s0 + srow;
      float g = __expf(cl - CUMS[(size_t)rh*SEQLEN + l]) * DTt[(size_t)rh*SEQLEN + l];
      const unsigned short* row = XTb + ((size_t)bi*SEQLEN + l)*CONV_DIM;
      ushort4 x0 = *(const ushort4*)(row + h*HEADDIM + cg);
      ushort4 x1 = *(const ushort4*)(row + h*HEADDIM + cg + 4);
      ushort4 b0 = *(const ushort4*)(row + D_INNER + cg);
      ushort4 b1 = *(const ushort4*)(row + D_INNER + cg + 4);
      Xb[cg+0][srow] = f2bf(g*bf2f(x0.x)); Xb[cg+1][srow] = f2bf(g*bf2f(x0.y));
      Xb[cg+2][srow] = f2bf(g*bf2f(x0.z)); Xb[cg+3][srow] = f2bf(g*bf2f(x0.w));
      Xb[cg+4][srow] = f2bf(g*bf2f(x1.x)); Xb[cg+5][srow] = f2bf(g*bf2f(x1.y));
      Xb[cg+6][srow] = f2bf(g*bf2f(x1.z)); Xb[cg+7][srow] = f2bf(g*bf2f(x1.w));
      Bb[cg+0][srow] = b0.x; Bb[cg+1][srow] = b0.y;
      Bb[cg+2][srow] = b0.z; Bb[cg+3][srow] = b0.w;
      Bb[cg+4][srow] = b1.x; Bb[cg+5][srow] = b1.y;
      Bb[cg+6][srow] = b1.z; Bb[cg+7][srow] = b1.w;
    }
    __syncthreads();
    short8 af = *(const short8*)&Xb[w*16 + fr][kq];
#pragma unroll
    for (int j = 0; j < 4; ++j) {
      short8 bf8 = *(const short8*)&Bb[j*16 + fr][kq];
      acc[j] = __builtin_amdgcn_mfma_f32_16x16x32_bf16(af, bf8, acc[j], 0, 0, 0);
    }
  }
  const int col = lane & 15;
  const int rg = (lane >> 4) * 4;
  size_t base = (((size_t)r*NCH + c)*NHEADS + h) * (size_t)(HEADDIM*D_STATE);
#pragma unroll
  for (int j = 0; j < 4; ++j)
#pragma unroll
    for (int q = 0; q < 4; ++q)
      SCH[base + (size_t)(w*16 + rg + q)*D_STATE + j*16 + col] = acc[j][q];
}

// ---------------- prefix-combine chunk states -> SPREV ----------------
__global__ __launch_bounds__(256) void state_combine_kernel(const float* __restrict__ SCH,
                                                            const float* __restrict__ CUMS,
                                                            float* __restrict__ SPREV) {
  int bid = blockIdx.x;
  int pq = bid & 3;
  int h = (bid >> 2) & 31;
  int r = bid >> 7;
  int tid = threadIdx.x;
  int p = pq*16 + (tid >> 4);
  int n = (tid & 15) * 4;
  float4 S = make_float4(0.f, 0.f, 0.f, 0.f);
  for (int c = 0; c < NCH; ++c) {
    size_t off = ((((size_t)r*NCH + c)*NHEADS + h)*HEADDIM + p)*D_STATE + n;
    *(float4*)(SPREV + off) = S;
    float dec = __expf(CUMS[((size_t)r*NHEADS + h)*SEQLEN + c*CHUNK + 255]);
    float4 v = *(const float4*)(SCH + off);
    S.x = dec*S.x + v.x; S.y = dec*S.y + v.y;
    S.z = dec*S.z + v.z; S.w = dec*S.w + v.w;
  }
}

// ---------------- Y = intra(triangular, MFMA) + inter (MFMA, fwd only), bf16 out ----------------
__global__ __launch_bounds__(256) void yscan_kernel(const unsigned short* __restrict__ XTb,
                                                    const float* __restrict__ DTt,
                                                    const float* __restrict__ CUMS,
                                                    const float* __restrict__ CBs,
                                                    const float* __restrict__ SPREV,
                                                    unsigned short* __restrict__ Yb16) {
  __shared__ unsigned short Xb[64][40];
  __shared__ float dts[CHUNK];
  __shared__ float cums[CHUNK];
  int tid = threadIdx.x;
  int lane = tid & 63;
  int w = tid >> 6;
  int c = blockIdx.x;
  int rh = blockIdx.y;
  int h = rh & 31;
  int r = rh >> 5;
  int bi = r & 1;
  dts[tid]  = DTt[(size_t)rh*SEQLEN + c*CHUNK + tid];
  cums[tid] = CUMS[(size_t)rh*SEQLEN + c*CHUNK + tid];
  __syncthreads();
  const int fr = lane & 15;
  const int kq = (lane >> 4) * 8;
  const int wt0 = w * 64;
  float ct[4];
#pragma unroll
  for (int i = 0; i < 4; ++i) ct[i] = cums[wt0 + i*16 + fr];
  floatx4 acc[4][4] = {};
  size_t cbbase = (((size_t)r*NCH + c) * CHUNK) * CHUNK;
  const int maxsl = 2*w + 1;
  for (int sl = 0; sl < 8; ++sl) {
    int s0 = sl * 32;
    __syncthreads();
    {
      int srow = tid >> 3;
      int p0 = (tid & 7) * 4;
      int L = c*CHUNK + s0 + srow;
      if (r >= 2) L = flip_l(L);
      const unsigned short* xrow = XTb + ((size_t)bi*SEQLEN + L)*CONV_DIM + h*HEADDIM;
#pragma unroll
      for (int half = 0; half < 2; ++half) {
        ushort4 v = *(const ushort4*)(xrow + p0 + half*32);
        Xb[p0 + half*32 + 0][srow] = v.x;
        Xb[p0 + half*32 + 1][srow] = v.y;
        Xb[p0 + half*32 + 2][srow] = v.z;
        Xb[p0 + half*32 + 3][srow] = v.w;
      }
    }
    __syncthreads();
    if (sl <= maxsl) {
      float cs[8], dtv[8];
#pragma unroll
      for (int j = 0; j < 8; ++j) { cs[j] = cums[s0 + kq + j]; dtv[j] = dts[s0 + kq + j]; }
      short8 bfr[4];
#pragma unroll
      for (int j = 0; j < 4; ++j)
        bfr[j] = *(const short8*)&Xb[j*16 + fr][kq];
#pragma unroll
      for (int i = 0; i < 4; ++i) {
        int t = wt0 + i*16 + fr;
        const float* cbrow = CBs + cbbase + (size_t)t*CHUNK + s0 + kq;
        float4 c0 = *(const float4*)cbrow;
        float4 c1 = *(const float4*)(cbrow + 4);
        float cb[8] = {c0.x,c0.y,c0.z,c0.w,c1.x,c1.y,c1.z,c1.w};
        short8 af;
#pragma unroll
        for (int j = 0; j < 8; ++j) {
          int s = s0 + kq + j;
          float wv = (s <= t) ? cb[j] * __expf(ct[i] - cs[j]) * dtv[j] : 0.f;
          af[j] = (short)f2bf(wv);
        }
#pragma unroll
        for (int j = 0; j < 4; ++j)
          acc[i][j] = __builtin_amdgcn_mfma_f32_16x16x32_bf16(af, bfr[j], acc[i][j], 0, 0, 0);
      }
    }
  }
  if (r < 2) {
    float ect[4];
#pragma unroll
    for (int i = 0; i < 4; ++i) ect[i] = __expf(ct[i]);
    const float* spbase = SPREV + (((size_t)r*NCH + c)*NHEADS + h) * (size_t)(HEADDIM*D_STATE);
#pragma unroll
    for (int ns = 0; ns < 2; ++ns) {
      int n0 = ns * 32;
      short8 bfr[4];
#pragma unroll
      for (int j = 0; j < 4; ++j) {
        const float* sp = spbase + (size_t)(j*16 + fr)*D_STATE + n0 + kq;
        float4 s0v = *(const float4*)sp;
        float4 s1v = *(const float4*)(sp + 4);
        short8 bb;
        bb[0]=(short)f2bf(s0v.x); bb[1]=(short)f2bf(s0v.y); bb[2]=(short)f2bf(s0v.z); bb[3]=(short)f2bf(s0v.w);
        bb[4]=(short)f2bf(s1v.x); bb[5]=(short)f2bf(s1v.y); bb[6]=(short)f2bf(s1v.z); bb[7]=(short)f2bf(s1v.w);
        bfr[j] = bb;
      }
#pragma unroll
      for (int i = 0; i < 4; ++i) {
        int t = wt0 + i*16 + fr;
        const unsigned short* crow = XTb + ((size_t)bi*SEQLEN + c*CHUNK + t)*CONV_DIM + D_INNER + GN + n0 + kq;
        ushort4 c0 = *(const ushort4*)crow;
        ushort4 c1 = *(const ushort4*)(crow + 4);
        short8 af;
        af[0]=(short)f2bf(bf2f(c0.x)*ect[i]); af[1]=(short)f2bf(bf2f(c0.y)*ect[i]);
        af[2]=(short)f2bf(bf2f(c0.z)*ect[i]); af[3]=(short)f2bf(bf2f(c0.w)*ect[i]);
        af[4]=(short)f2bf(bf2f(c1.x)*ect[i]); af[5]=(short)f2bf(bf2f(c1.y)*ect[i]);
        af[6]=(short)f2bf(bf2f(c1.z)*ect[i]); af[7]=(short)f2bf(bf2f(c1.w)*ect[i]);
#pragma unroll
        for (int j = 0; j < 4; ++j)
          acc[i][j] = __builtin_amdgcn_mfma_f32_16x16x32_bf16(af, bfr[j], acc[i][j], 0, 0, 0);
      }
    }
  }
  // bf16 epilogue: per-wave LDS transpose (reuse Xb; barrier — wave 0 races ahead)
  __syncthreads();
  unsigned short* Ew = (unsigned short*)Xb + w * 1024;
  const int rg = (lane >> 4) * 4;
  const int rr = lane >> 3;
  const int c8 = (lane & 7) * 8;
  size_t ybase = ((size_t)r*SEQLEN + c*CHUNK)*D_INNER + h*HEADDIM;
#pragma unroll
  for (int i = 0; i < 4; ++i) {
#pragma unroll
    for (int q = 0; q < 4; ++q)
#pragma unroll
      for (int j = 0; j < 4; ++j)
        Ew[(rg + q) * 64 + j * 16 + fr] = f2bf(acc[i][j][q]);
    ushort8v v0 = *(const ushort8v*)&Ew[rr * 64 + c8];
    ushort8v v1 = *(const ushort8v*)&Ew[(rr + 8) * 64 + c8];
    *(ushort8v*)(Yb16 + ybase + (size_t)(wt0 + i*16 + rr) * D_INNER + c8) = v0;
    *(ushort8v*)(Yb16 + ybase + (size_t)(wt0 + i*16 + rr + 8) * D_INNER + c8) = v1;
  }
}

// ---------------- shifts + x_res + RMSNorm + gate (vectorized, -> bf16) ----------------
__global__ __launch_bounds__(256) void combine_kernel(const unsigned short* __restrict__ Y,
                                                      const unsigned short* __restrict__ XTb,
                                                      const float* __restrict__ FCD,
                                                      const float* __restrict__ Dp,
                                                      const unsigned short* __restrict__ Zb,
                                                      const float* __restrict__ norm_w,
                                                      unsigned short* __restrict__ YPb) {
  __shared__ float red[256];
  int row = blockIdx.x;
  int bi = row >> 11;
  int l = row & 2047;
  int s = l >> 3, fr = l & 7;
  int tid = threadIdx.x;
  int d0 = tid * 8;
  const unsigned short* yf = (l >= 1) ? Y + ((size_t)bi*SEQLEN + (l-1))*D_INNER + d0 : nullptr;
  const unsigned short* yr = (s >= 1) ? Y + ((size_t)(2+bi)*SEQLEN + ((s-1)*8 + (7-fr)))*D_INNER + d0 : nullptr;
  const unsigned short* xr = XTb + ((size_t)row)*CONV_DIM + d0;
  float fcv = FCD[(size_t)row*NHEADS + (d0 >> 6)] + Dp[d0 >> 6];
  ushort8v xv8 = *(const ushort8v*)xr;
  float v[8];
#pragma unroll
  for (int q = 0; q < 8; ++q) v[q] = bf2f(xv8[q]) * fcv;
  if (yf) {
    ushort8v a = *(const ushort8v*)yf;
#pragma unroll
    for (int q = 0; q < 8; ++q) v[q] += bf2f(a[q]);
  }
  if (yr) {
    ushort8v a = *(const ushort8v*)yr;
#pragma unroll
    for (int q = 0; q < 8; ++q) v[q] += bf2f(a[q]);
  }
  float ss = 0.f;
#pragma unroll
  for (int q = 0; q < 8; ++q) ss += v[q] * v[q];
  red[tid] = ss;
  __syncthreads();
  for (int ofs = 128; ofs > 0; ofs >>= 1) {
    if (tid < ofs) red[tid] += red[tid + ofs];
    __syncthreads();
  }
  float rs = rsqrtf(red[0] / (float)D_INNER + 1e-5f);
  ushort8v zv8 = *(const ushort8v*)(Zb + ((size_t)row)*ZLD + d0);
  float4 nw0 = *(const float4*)(norm_w + d0);
  float4 nw1 = *(const float4*)(norm_w + d0 + 4);
  float nw[8] = {nw0.x,nw0.y,nw0.z,nw0.w,nw1.x,nw1.y,nw1.z,nw1.w};
  ushort8v o;
#pragma unroll
  for (int q = 0; q < 8; ++q)
    o[q] = f2bf(v[q] * rs * nw[q] * silu_f(bf2f(zv8[q])));
  *(ushort8v*)(YPb + (size_t)row*D_INNER + d0) = o;
}

extern "C" void kernel_launch(void* const* d_in, const int* in_sizes, int n_in,
                              void* d_out, int out_size, void* d_ws, size_t ws_size,
                              hipStream_t stream) {
  (void)in_sizes; (void)n_in; (void)out_size; (void)ws_size;
  const float* u          = (const float*)d_in[0];
  const float* in_proj_w  = (const float*)d_in[1];
  const float* conv_sp_w  = (const float*)d_in[2];
  const float* conv_sp_b  = (const float*)d_in[3];
  const float* conv_tp_w  = (const float*)d_in[4];
  const float* conv_tp_b  = (const float*)d_in[5];
  const float* dt_bias    = (const float*)d_in[6];
  const float* A_log      = (const float*)d_in[7];
  const float* Dp         = (const float*)d_in[8];
  const float* fc_D_w     = (const float*)d_in[9];
  const float* norm_w     = (const float*)d_in[10];
  const float* out_proj_w = (const float*)d_in[11];
  float* out = (float*)d_out;
  float* ws = (float*)d_ws;

  // workspace layout (f32-element offsets; Z/XT/Y regions hold bf16)
  float* Z     = ws;                       // 17,825,792 slots (bf16 uses half)
  float* SH    = Z     + 17825792ULL;      // 9,437,184  (CBs -> YPb)
  float* XT    = SH    + 9437184ULL;       // 9,437,184  (bf16 uses half)
  float* DTt   = XT    + 9437184ULL;       // 262,144
  float* Yb    = DTt   + 262144ULL;        // 16,777,216 (bf16 Y in first half; SCH; Wob tail)
  float* SPREV = Yb    + 16777216ULL;      // 2,097,152
  float* FCD   = SPREV + 2097152ULL;       // 131,072
  float* DTraw = FCD   + 131072ULL;        // 262,144
  float* CUMS  = DTraw + 262144ULL;        // 262,144

  unsigned short* Zb   = (unsigned short*)Z;
  unsigned short* XTb  = (unsigned short*)XT;
  unsigned short* Yb16 = (unsigned short*)Yb;            // floats [0, 8,388,608)
  unsigned short* Ub   = (unsigned short*)Yb;            // staging (dead before yscan)
  unsigned short* Wb   = (unsigned short*)Yb + 4194304ULL;
  float* SCH = Yb + 8388608ULL;                          // floats [8,388,608, 10,485,760)
  unsigned short* Wob = (unsigned short*)(Yb + 10485760ULL);  // always-free tail slice
  unsigned short* YPb = (unsigned short*)SH;

  cast3_bf16_kernel<<<10496, 256, 0, stream>>>(u, Ub, 4096, in_proj_w, Wb, 4352,
                                               out_proj_w, Wob);
  gemm_bk64_bf16out<<<dim3(34, 32), 256, 0, stream>>>(Ub, 1024, Wb, 1024, Zb, ZLD, 1024);
  gemm_ts_mfma<<<256, 256, 0, stream>>>(Ub, 1024, in_proj_w + 4352ULL*1024, 1024,
                                        DTraw, 64, 64, 1024);
  dtscan_kernel<<<1024, 256, 0, stream>>>(DTraw, dt_bias, A_log, DTt, CUMS);
  conv_fused2_kernel<<<dim3(18, 32, 2), 256, 0, stream>>>(Zb, conv_sp_w, conv_sp_b,
                                                          conv_tp_w, conv_tp_b, XTb);
  gemm_ts_mfma<<<256, 256, 0, stream>>>(XTb, CONV_DIM, fc_D_w, 2048,
                                        FCD, 32, 32, 2048);
  cb_kernel<<<dim3(16, 8, 4), 256, 0, stream>>>(XTb, SH);
  chunk_state_kernel<<<dim3(NCH, NHEADS, 2), 256, 0, stream>>>(XTb, DTt, CUMS, SCH);
  state_combine_kernel<<<256, 256, 0, stream>>>(SCH, CUMS, SPREV);
  yscan_kernel<<<dim3(8, 128), 256, 0, stream>>>(XTb, DTt, CUMS, SH, SPREV, Yb16);
  combine_kernel<<<4096, 256, 0, stream>>>(Yb16, XTb, FCD, Dp, Zb, norm_w, YPb);
  gemm_m64_f32<<<dim3(8, 64), 256, 0, stream>>>(YPb, 2048, Wob, 2048, out, 1024, 2048);
}